// Round 15
// baseline (618.212 us; speedup 1.0000x reference)
//
#include <hip/hip_runtime.h>
#include <hip/hip_bf16.h>
#include <math.h>

#define NB 4
#define B  2048
#define L  168
#define DI 9
#define H  96
#define N2 48

#define ZSTR2 132   // mix2/fc1m zs row stride (ushorts): 128 + 4 pad
#define CZ 68       // conv3 zs row stride (ushorts): 64 + 4 pad (conflict-free, verified r12)

typedef short short8 __attribute__((ext_vector_type(8)));
typedef float f32x4  __attribute__((ext_vector_type(4)));
typedef unsigned short u16x8 __attribute__((ext_vector_type(8)));
typedef unsigned short u16x4 __attribute__((ext_vector_type(4)));

// exact-algebra gelu: 0.5x(1+tanh(y)) == x*(1 - 1/(exp(2y)+1)), exp via native v_exp_f32 (2^x)
__device__ __forceinline__ float gelu_f(float x) {
    float x2 = x * x;
    float e  = __builtin_amdgcn_exp2f(x * fmaf(0.1029432225f, x2, 2.3022081899f));
    float r  = __builtin_amdgcn_rcpf(e + 1.0f);
    return x * (1.0f - r);
}

__device__ __forceinline__ unsigned short bf16_rne(float x) {
    unsigned u = __float_as_uint(x);
    return (unsigned short)((u + 0x7FFFu + ((u >> 16) & 1u)) >> 16);
}
__device__ __forceinline__ float b2f(unsigned short v) {
    return __uint_as_float((unsigned)v << 16);
}

// ---------------- S4D kernel generation: K[i][h][l] ----------------
__global__ void kgen_kernel(const float* __restrict__ log_dt, const float* __restrict__ lar,
                            const float* __restrict__ aim, const float* __restrict__ cre,
                            const float* __restrict__ cim, float* __restrict__ K)
{
    const int ih   = blockIdx.x;
    const int lane = threadIdx.x;
    float ctre = 0.f, ctim = 0.f, pre = 0.f, pim = 0.f, mre = 0.f, mim = 0.f;
    if (lane < N2) {
        float dt  = expf(log_dt[ih]);
        int   idx = ih * N2 + lane;
        float reA = -expf(lar[idx]);
        float imA = aim[idx];
        float dre = dt * reA, dim = dt * imA;
        float er  = expf(dre);
        float sv, cv;
        sincosf(dim, &sv, &cv);
        mre = er * cv; mim = er * sv;
        float nre = mre - 1.0f, nim = mim;
        float den = reA * reA + imA * imA;
        float tre = (nre * reA + nim * imA) / den;
        float tim = (nim * reA - nre * imA) / den;
        float cr = cre[idx], ci = cim[idx];
        ctre = cr * tre - ci * tim;
        ctim = cr * tim + ci * tre;
        pre = 1.0f; pim = 0.0f;
    }
    float* Kr = K + ih * L;
    for (int l = 0; l < L; ++l) {
        float term = ctre * pre - ctim * pim;
        #pragma unroll
        for (int off = 32; off > 0; off >>= 1) term += __shfl_xor(term, off, 64);
        if (lane == 0) Kr[l] = 2.0f * term;
        float nr = pre * mre - pim * mim;
        float ni = pre * mim + pim * mre;
        pre = nr; pim = ni;
    }
}

// ---------------- prepack W (layers of 96x96, row=k, col=out) into MFMA A-frags hi/lo ----------------
__global__ void wprep_kernel(const float* __restrict__ wout, short* __restrict__ wfrag, int ntask)
{
    int idx = blockIdx.x * 256 + threadIdx.x;
    if (idx >= ntask) return;
    int layer = idx / 9216;  int rem  = idx - layer * 9216;
    int ch    = rem / 3072;  int rem2 = rem - ch * 3072;
    int m     = rem2 / 512;  int rem3 = rem2 - m * 512;
    int s     = rem3 / 256;  int rem4 = rem3 - s * 256;
    int lane  = rem4 / 4;    int d    = rem4 - lane * 4;
    int g = lane >> 4, c = lane & 15;
    int k  = ch * 32 + g * 8 + 2 * d;
    int hp = m * 16 + c;
    const float* Wl = wout + (size_t)layer * H * H;
    float w0 = Wl[k * H + hp];
    float w1 = Wl[(k + 1) * H + hp];
    unsigned short b0, b1;
    if (s == 0) { b0 = bf16_rne(w0); b1 = bf16_rne(w1); }
    else {
        unsigned short h0 = bf16_rne(w0), h1 = bf16_rne(w1);
        b0 = bf16_rne(w0 - b2f(h0));
        b1 = bf16_rne(w1 - b2f(h1));
    }
    wfrag[idx * 2]     = (short)b0;
    wfrag[idx * 2 + 1] = (short)b1;
}

// ---------------- Toeplitz A-fragments (hi-only bf16): T[l][l'] = K[l-l'] ----------------
__global__ void tgen_kernel(const float* __restrict__ Kg, short* __restrict__ tfrag)
{
    static const int kmaxA[11] = {0, 0, 1, 1, 2, 2, 3, 3, 4, 4, 5};
    static const int toffA[11] = {0, 1, 2, 4, 6, 9, 12, 16, 20, 25, 30};
    int idx = blockIdx.x * 256 + threadIdx.x;          // 96*66*64 tasks
    if (idx >= 96 * 66 * 64) return;
    int lane = idx & 63;
    int t    = (idx >> 6) % 66;
    int h    = (idx >> 6) / 66;
    int mi = t / 6, ki = t - mi * 6;
    if (ki > kmaxA[mi]) return;
    int g = lane >> 4, c = lane & 15;
    int row = mi * 16 + c;
    short8 a;
    #pragma unroll
    for (int j = 0; j < 8; ++j) {
        int kk = ki * 32 + g * 8 + j;
        int d  = row - kk;
        float val = (row < L && d >= 0) ? Kg[h * L + d] : 0.0f;
        a[j] = (short)bf16_rne(val);
    }
    short8* dst = (short8*)tfrag + (size_t)(h * 36 + toffA[mi] + ki) * 64;
    dst[lane] = a;
}

// ---------------- compose decW into fc1W ----------------
__launch_bounds__(256)
__global__ void wcomp_kernel(const float* __restrict__ decW, const float* __restrict__ decb,
                             const float* __restrict__ fc1W, float* __restrict__ wcs,
                             float* __restrict__ cbpart)
{
    __shared__ float Bs[96 * 100];
    const int tid = threadIdx.x;
    const int l   = blockIdx.x;
    for (int e = tid; e < 96 * 96; e += 256) {
        int h = e / 96, p = e - h * 96;
        Bs[h * 100 + p] = fc1W[(size_t)(l * 96 + h) * 96 + p];
    }
    __syncthreads();
    const int pt = tid & 31;
    const int kt = tid >> 5;
    float acc[12][3];
    #pragma unroll
    for (int kk = 0; kk < 12; ++kk)
        #pragma unroll
        for (int j = 0; j < 3; ++j) acc[kk][j] = 0.f;
    for (int h = 0; h < 96; ++h) {
        float dw[12];
        #pragma unroll
        for (int kk = 0; kk < 12; ++kk) dw[kk] = decW[(kt + 8 * kk) * 96 + h];
        float bs[3];
        #pragma unroll
        for (int j = 0; j < 3; ++j) bs[j] = Bs[h * 100 + pt + 32 * j];
        #pragma unroll
        for (int kk = 0; kk < 12; ++kk)
            #pragma unroll
            for (int j = 0; j < 3; ++j) acc[kk][j] = fmaf(dw[kk], bs[j], acc[kk][j]);
    }
    float* wl = wcs + (size_t)l * 9216;
    #pragma unroll
    for (int kk = 0; kk < 12; ++kk)
        #pragma unroll
        for (int j = 0; j < 3; ++j)
            wl[(kt + 8 * kk) * 96 + pt + 32 * j] = acc[kk][j];
    if (kt == 0) {
        #pragma unroll
        for (int j = 0; j < 3; ++j) {
            float s = 0.f;
            for (int h = 0; h < 96; ++h) s = fmaf(decb[h], Bs[h * 100 + pt + 32 * j], s);
            cbpart[l * 96 + pt + 32 * j] = s;
        }
    }
}

__global__ void cbias_red_kernel(const float* __restrict__ cbpart, const float* __restrict__ fc1b,
                                 float* __restrict__ cbias)
{
    int p = threadIdx.x;
    if (p < 96) {
        float s = fc1b[p];
        for (int l = 0; l < L; ++l) s += cbpart[l * 96 + p];
        cbias[p] = s;
    }
}

// ---------------- encoder into (h,l,b) bf16 ----------------
__launch_bounds__(256)
__global__ void enc2_kernel(const float* __restrict__ x, const float* __restrict__ W,
                            const float* __restrict__ bias, unsigned short* __restrict__ hb2)
{
    __shared__ float Ws[DI * H];
    __shared__ float bs[H];
    const int tid = threadIdx.x;
    const int l   = blockIdx.x;
    const int b0  = blockIdx.y * 256;
    for (int e = tid; e < DI * H; e += 256) Ws[e] = W[e];
    if (tid < H) bs[tid] = bias[tid];
    __syncthreads();
    float xv[DI];
    const float* xr = x + (size_t)(b0 + tid) * (L * DI) + l * DI;
    #pragma unroll
    for (int k = 0; k < DI; ++k) xv[k] = xr[k];
    for (int h = 0; h < H; ++h) {
        float a = bs[h];
        #pragma unroll
        for (int k = 0; k < DI; ++k) a = fmaf(xv[k], Ws[k * H + h], a);
        hb2[((size_t)h * L + l) * B + b0 + tid] = bf16_rne(a);
    }
}

// ---------------- conv via Toeplitz MFMA + skip + GELU: chunk 64, batched Tf loads ----------------
__launch_bounds__(256, 4)
__global__ void conv3_kernel(const unsigned short* __restrict__ hb2, const short* __restrict__ tfrag,
                             const float* __restrict__ Dsk, unsigned short* __restrict__ z2)
{
    static const int toffA[11] = {0, 1, 2, 4, 6, 9, 12, 16, 20, 25, 30};
    __shared__ __align__(16) unsigned short zs[192 * CZ];   // 26.1 KB
    const int tid  = threadIdx.x;
    const int w    = tid >> 6;
    const int lane = tid & 63;
    const int g    = lane >> 4;
    const int cc   = lane & 15;
    const int h    = blockIdx.x;
    const int b0   = blockIdx.y * 64;

    for (int e = tid; e < 168 * 8; e += 256) {
        int lp = e >> 3, b8 = e & 7;
        u16x8 v = *(const u16x8*)(hb2 + ((size_t)h * L + lp) * B + b0 + b8 * 8);
        *(u16x4*)(&zs[lp * CZ + b8 * 8])     = (u16x4){v[0], v[1], v[2], v[3]};
        *(u16x4*)(&zs[lp * CZ + b8 * 8 + 4]) = (u16x4){v[4], v[5], v[6], v[7]};
    }
    for (int e = tid; e < 24 * 8; e += 256) {
        int lp = 168 + (e >> 3), b8 = e & 7;
        *(u16x4*)(&zs[lp * CZ + b8 * 8])     = (u16x4){0, 0, 0, 0};
        *(u16x4*)(&zs[lp * CZ + b8 * 8 + 4]) = (u16x4){0, 0, 0, 0};
    }
    __syncthreads();

    f32x4 acc[11];
    #pragma unroll
    for (int mi = 0; mi < 11; ++mi) acc[mi] = (f32x4){0.f, 0.f, 0.f, 0.f};

    const int col = w * 16 + cc;
    const short8* Tbase = (const short8*)tfrag + (size_t)h * 36 * 64 + lane;

    #pragma unroll
    for (int ki = 0; ki < 6; ++ki) {
        short8 bh;
        #pragma unroll
        for (int j = 0; j < 8; ++j)
            bh[j] = (short)zs[(ki * 32 + g * 8 + j) * CZ + col];
        short8 tf[11];
        #pragma unroll
        for (int mi = 0; mi < 11; ++mi)
            if (mi >= 2 * ki)
                tf[mi] = Tbase[(size_t)(toffA[mi] + ki) * 64];
        #pragma unroll
        for (int mi = 0; mi < 11; ++mi)
            if (mi >= 2 * ki)
                acc[mi] = __builtin_amdgcn_mfma_f32_16x16x32_bf16(tf[mi], bh, acc[mi], 0, 0, 0);
    }

    const float ds = Dsk[h];
    #pragma unroll
    for (int mi = 0; mi < 11; ++mi) {
        #pragma unroll
        for (int r = 0; r < 4; ++r) {
            int l = mi * 16 + g * 4 + r;
            if (l < L) {
                float uu = b2f(zs[l * CZ + col]);
                float zv = gelu_f(fmaf(ds, uu, acc[mi][r]));
                zs[l * CZ + col] = bf16_rne(zv);
            }
        }
    }
    __syncthreads();
    for (int e = tid; e < 168 * 8; e += 256) {
        int lp = e >> 3, b8 = e & 7;
        u16x4 a = *(const u16x4*)(&zs[lp * CZ + b8 * 8]);
        u16x4 b = *(const u16x4*)(&zs[lp * CZ + b8 * 8 + 4]);
        u16x8 v = {a[0], a[1], a[2], a[3], b[0], b[1], b[2], b[3]};
        *(u16x8*)(z2 + ((size_t)h * L + lp) * B + b0 + b8 * 8) = v;
    }
}

// ---------------- W_out GEMM + bias + residual + LN: 8 waves, chunk 128, 2-l T14 pipeline ----------------
__launch_bounds__(512)
__global__ void mix2_kernel(const unsigned short* __restrict__ z2, unsigned short* __restrict__ hb2,
                            const short* __restrict__ wfrag, const float* __restrict__ bout,
                            const float* __restrict__ lnw, const float* __restrict__ lnb)
{
    __shared__ __align__(16) unsigned short zs[H * ZSTR2];   // z (MFMA B operand)
    __shared__ __align__(16) unsigned short rs[H * ZSTR2];   // residual in, LN output out
    const int tid  = threadIdx.x;
    const int w    = tid >> 6;
    const int lane = tid & 63;
    const int g    = lane >> 4;
    const int cc   = lane & 15;
    const int l0   = blockIdx.x * 2;
    const int b0   = blockIdx.y * 128;

    // stage half 0 directly to LDS
    for (int e = tid; e < 96 * 16; e += 512) {
        int hh = e >> 4, b8 = e & 15;
        u16x8 v = *(const u16x8*)(z2 + ((size_t)hh * L + l0) * B + b0 + b8 * 8);
        *(u16x4*)(&zs[hh * ZSTR2 + b8 * 8])     = (u16x4){v[0], v[1], v[2], v[3]};
        *(u16x4*)(&zs[hh * ZSTR2 + b8 * 8 + 4]) = (u16x4){v[4], v[5], v[6], v[7]};
    }
    for (int e = tid; e < 96 * 16; e += 512) {
        int hh = e >> 4, b8 = e & 15;
        u16x8 v = *(const u16x8*)(hb2 + ((size_t)hh * L + l0) * B + b0 + b8 * 8);
        *(u16x4*)(&rs[hh * ZSTR2 + b8 * 8])     = (u16x4){v[0], v[1], v[2], v[3]};
        *(u16x4*)(&rs[hh * ZSTR2 + b8 * 8 + 4]) = (u16x4){v[4], v[5], v[6], v[7]};
    }
    __syncthreads();

    const int col = w * 16 + cc;
    u16x8 zr[3], rr[3];

    for (int half = 0; half < 2; ++half) {
        const int l = l0 + half;
        if (half == 0) {
            // T14: issue next-l global loads into regs, consumed after this l's store
            #pragma unroll
            for (int i = 0; i < 3; ++i) {
                int e = tid + i * 512;
                int hh = e >> 4, b8 = e & 15;
                zr[i] = *(const u16x8*)(z2 + ((size_t)hh * L + l0 + 1) * B + b0 + b8 * 8);
                rr[i] = *(const u16x8*)(hb2 + ((size_t)hh * L + l0 + 1) * B + b0 + b8 * 8);
            }
        }

        f32x4 acc[6];
        #pragma unroll
        for (int m = 0; m < 6; ++m) acc[m] = (f32x4){0.f, 0.f, 0.f, 0.f};

        #pragma unroll
        for (int ks = 0; ks < 3; ++ks) {
            short8 bh;
            #pragma unroll
            for (int j = 0; j < 8; ++j)
                bh[j] = (short)zs[(ks * 32 + g * 8 + j) * ZSTR2 + col];
            const short8* Wf = (const short8*)(wfrag) + ks * 12 * 64;
            short8 wa[12];
            #pragma unroll
            for (int m = 0; m < 12; ++m) wa[m] = Wf[m * 64 + lane];
            #pragma unroll
            for (int m = 0; m < 6; ++m) {
                acc[m] = __builtin_amdgcn_mfma_f32_16x16x32_bf16(wa[2 * m + 1], bh, acc[m], 0, 0, 0);
                acc[m] = __builtin_amdgcn_mfma_f32_16x16x32_bf16(wa[2 * m],     bh, acc[m], 0, 0, 0);
            }
        }

        // epilogue: +bias +residual (LDS), LN over h', write back to rs (cols wave-partitioned)
        float vals[6][4];
        float s = 0.f, q = 0.f;
        #pragma unroll
        for (int m = 0; m < 6; ++m) {
            float4 B4 = *(const float4*)(bout + m * 16 + g * 4);
            float bo[4] = {B4.x, B4.y, B4.z, B4.w};
            #pragma unroll
            for (int r = 0; r < 4; ++r) {
                int hr = m * 16 + g * 4 + r;
                float res = b2f(rs[hr * ZSTR2 + col]);
                float v = acc[m][r] + bo[r] + res;
                vals[m][r] = v;
                s += v; q += v * v;
            }
        }
        s += __shfl_xor(s, 16, 64); q += __shfl_xor(q, 16, 64);
        s += __shfl_xor(s, 32, 64); q += __shfl_xor(q, 32, 64);
        float mean = s * (1.0f / 96.0f);
        float var  = q * (1.0f / 96.0f) - mean * mean;
        float rstd = rsqrtf(var + 1e-5f);
        #pragma unroll
        for (int m = 0; m < 6; ++m) {
            float4 W4 = *(const float4*)(lnw + m * 16 + g * 4);
            float4 Bb = *(const float4*)(lnb + m * 16 + g * 4);
            float wv[4] = {W4.x, W4.y, W4.z, W4.w};
            float bv[4] = {Bb.x, Bb.y, Bb.z, Bb.w};
            #pragma unroll
            for (int r = 0; r < 4; ++r) {
                int hr = m * 16 + g * 4 + r;
                rs[hr * ZSTR2 + col] = bf16_rne(fmaf((vals[m][r] - mean) * rstd, wv[r], bv[r]));
            }
        }
        __syncthreads();
        // coalesced store of this l
        for (int e = tid; e < 96 * 16; e += 512) {
            int hh = e >> 4, b8 = e & 15;
            u16x4 a = *(const u16x4*)(&rs[hh * ZSTR2 + b8 * 8]);
            u16x4 b = *(const u16x4*)(&rs[hh * ZSTR2 + b8 * 8 + 4]);
            u16x8 v = {a[0], a[1], a[2], a[3], b[0], b[1], b[2], b[3]};
            *(u16x8*)(hb2 + ((size_t)hh * L + l) * B + b0 + b8 * 8) = v;
        }
        if (half == 0) {
            __syncthreads();   // all store-phase LDS reads retired before overwrite
            #pragma unroll
            for (int i = 0; i < 3; ++i) {
                int e = tid + i * 512;
                int hh = e >> 4, b8 = e & 15;
                *(u16x4*)(&zs[hh * ZSTR2 + b8 * 8])     = (u16x4){zr[i][0], zr[i][1], zr[i][2], zr[i][3]};
                *(u16x4*)(&zs[hh * ZSTR2 + b8 * 8 + 4]) = (u16x4){zr[i][4], zr[i][5], zr[i][6], zr[i][7]};
                *(u16x4*)(&rs[hh * ZSTR2 + b8 * 8])     = (u16x4){rr[i][0], rr[i][1], rr[i][2], rr[i][3]};
                *(u16x4*)(&rs[hh * ZSTR2 + b8 * 8 + 4]) = (u16x4){rr[i][4], rr[i][5], rr[i][6], rr[i][7]};
            }
            __syncthreads();
        }
    }
}

// ---------------- fc1 via MFMA, split-K over 42, T14 pipelined over 4 l ----------------
__launch_bounds__(256)
__global__ void fc1m_kernel(const unsigned short* __restrict__ hb2, const short* __restrict__ wcfrag,
                            float* __restrict__ partial)
{
    __shared__ __align__(16) unsigned short zs[H * ZSTR2];
    const int tid  = threadIdx.x;
    const int w    = tid >> 6;
    const int lane = tid & 63;
    const int g    = lane >> 4;
    const int cc   = lane & 15;
    const int ksp  = blockIdx.x;
    const int b0   = blockIdx.y * 128;

    f32x4 acc[2][6];
    #pragma unroll
    for (int n2 = 0; n2 < 2; ++n2)
        #pragma unroll
        for (int m = 0; m < 6; ++m) acc[n2][m] = (f32x4){0.f, 0.f, 0.f, 0.f};

    // stage il=0 directly
    for (int e = tid; e < 96 * 16; e += 256) {
        int hh = e >> 4, b8 = e & 15;
        u16x8 v = *(const u16x8*)(hb2 + ((size_t)hh * L + ksp * 4) * B + b0 + b8 * 8);
        *(u16x4*)(&zs[hh * ZSTR2 + b8 * 8])     = (u16x4){v[0], v[1], v[2], v[3]};
        *(u16x4*)(&zs[hh * ZSTR2 + b8 * 8 + 4]) = (u16x4){v[4], v[5], v[6], v[7]};
    }
    __syncthreads();

    u16x8 pr[6];
    for (int il = 0; il < 4; ++il) {
        const int l = ksp * 4 + il;
        if (il < 3) {
            #pragma unroll
            for (int i = 0; i < 6; ++i) {
                int e = tid + i * 256;
                int hh = e >> 4, b8 = e & 15;
                pr[i] = *(const u16x8*)(hb2 + ((size_t)hh * L + l + 1) * B + b0 + b8 * 8);
            }
        }
        for (int ksl = 0; ksl < 3; ++ksl) {
            short8 bh[2];
            #pragma unroll
            for (int n2 = 0; n2 < 2; ++n2) {
                int col = (w * 2 + n2) * 16 + cc;
                #pragma unroll
                for (int j = 0; j < 8; ++j)
                    bh[n2][j] = (short)zs[(ksl * 32 + g * 8 + j) * ZSTR2 + col];
            }
            const short8* Wf = (const short8*)(wcfrag) + (size_t)(l * 3 + ksl) * 768;
            short8 wa[12];
            #pragma unroll
            for (int m = 0; m < 12; ++m) wa[m] = Wf[m * 64 + lane];
            #pragma unroll
            for (int m = 0; m < 6; ++m) {
                #pragma unroll
                for (int n2 = 0; n2 < 2; ++n2) {
                    acc[n2][m] = __builtin_amdgcn_mfma_f32_16x16x32_bf16(wa[2 * m + 1], bh[n2], acc[n2][m], 0, 0, 0);
                    acc[n2][m] = __builtin_amdgcn_mfma_f32_16x16x32_bf16(wa[2 * m],     bh[n2], acc[n2][m], 0, 0, 0);
                }
            }
        }
        __syncthreads();           // MFMA LDS reads done
        if (il < 3) {
            #pragma unroll
            for (int i = 0; i < 6; ++i) {
                int e = tid + i * 256;
                int hh = e >> 4, b8 = e & 15;
                *(u16x4*)(&zs[hh * ZSTR2 + b8 * 8])     = (u16x4){pr[i][0], pr[i][1], pr[i][2], pr[i][3]};
                *(u16x4*)(&zs[hh * ZSTR2 + b8 * 8 + 4]) = (u16x4){pr[i][4], pr[i][5], pr[i][6], pr[i][7]};
            }
            __syncthreads();
        }
    }

    #pragma unroll
    for (int n2 = 0; n2 < 2; ++n2) {
        int gb = b0 + (w * 2 + n2) * 16 + cc;
        #pragma unroll
        for (int m = 0; m < 6; ++m) {
            *(float4*)&partial[((size_t)ksp * B + gb) * 96 + m * 16 + g * 4] =
                make_float4(acc[n2][m][0], acc[n2][m][1], acc[n2][m][2], acc[n2][m][3]);
        }
    }
}

__global__ void fc1red_kernel(const float* __restrict__ partial, const float* __restrict__ cbias,
                              float* __restrict__ t1)
{
    int o = blockIdx.x * 256 + threadIdx.x;
    int p = o % 96;
    float s = cbias[p];
    #pragma unroll 6
    for (int k = 0; k < 42; ++k) s += partial[(size_t)k * (B * 96) + o];
    t1[o] = s;
}

__launch_bounds__(256)
__global__ void fc2_kernel(const float* __restrict__ t1, const float* __restrict__ W,
                           const float* __restrict__ fb, float* __restrict__ out)
{
    __shared__ float Ws[96 * 100];
    const int tid = threadIdx.x;
    for (int e = tid; e < 96 * 96; e += 256) Ws[(e / 96) * 100 + (e % 96)] = W[e];
    __syncthreads();
    int o = blockIdx.x * 256 + tid;
    int b = o / 96, p = o - b * 96;
    const float* tr = t1 + b * 96;
    float acc = fb[p];
    #pragma unroll 4
    for (int h = 0; h < 96; ++h) acc = fmaf(tr[h], Ws[h * 100 + p], acc);
    out[o] = acc;
}

extern "C" void kernel_launch(void* const* d_in, const int* in_sizes, int n_in,
                              void* d_out, int out_size, void* d_ws, size_t ws_size,
                              hipStream_t stream)
{
    const float* x      = (const float*)d_in[0];
    const float* encW   = (const float*)d_in[1];
    const float* encb   = (const float*)d_in[2];
    const float* log_dt = (const float*)d_in[3];
    const float* lar    = (const float*)d_in[4];
    const float* aim    = (const float*)d_in[5];
    const float* cre    = (const float*)d_in[6];
    const float* cim    = (const float*)d_in[7];
    const float* dsk    = (const float*)d_in[8];
    const float* wout   = (const float*)d_in[9];
    const float* boutp  = (const float*)d_in[10];
    const float* lnw    = (const float*)d_in[11];
    const float* lnb    = (const float*)d_in[12];
    const float* decW   = (const float*)d_in[13];
    const float* decb   = (const float*)d_in[14];
    const float* fc1W   = (const float*)d_in[15];
    const float* fc1b   = (const float*)d_in[16];
    const float* fc2W   = (const float*)d_in[17];
    const float* fc2b   = (const float*)d_in[18];

    // ws layout (max end = 143 MiB, proven envelope):
    char*           ws      = (char*)d_ws;
    float*          K       = (float*)(ws);                              // 258 KB
    short*          wfrag   = (short*)(ws + ((size_t)384 << 10));        // 147 KB
    float*          t1      = (float*)(ws + ((size_t)1 << 20));          // 786 KB
    float*          cbpart  = (float*)(ws + ((size_t)1 << 20) + (900 << 10)); // 64.5 KB
    float*          cbias   = (float*)(ws + ((size_t)1 << 20) + (980 << 10)); // 384 B
    short*          wcfrag  = (short*)(ws + ((size_t)2 << 20));          // 6.19 MB
    short*          tfrag   = (short*)(ws + ((size_t)9 << 20));          // 3.38 MB (hi-only)
    float*          wcs     = (float*)(ws + ((size_t)9 << 20));          // 6.19 MB, dead before tgen (alias)
    unsigned short* hb2     = (unsigned short*)(ws + ((size_t)16 << 20)); // 63.0 MiB (h,l,b) bf16
    unsigned short* z2      = (unsigned short*)(ws + ((size_t)80 << 20)); // 63.0 MiB (h,l,b) bf16
    float*          partial = (float*)(ws + ((size_t)80 << 20));          // 33 MiB, aliases z2

    kgen_kernel<<<NB * H, 64, 0, stream>>>(log_dt, lar, aim, cre, cim, K);
    wprep_kernel<<<144, 256, 0, stream>>>(wout, wfrag, NB * 9216);
    wcomp_kernel<<<L, 256, 0, stream>>>(decW, decb, fc1W, wcs, cbpart);
    wprep_kernel<<<6048, 256, 0, stream>>>(wcs, wcfrag, L * 9216);
    cbias_red_kernel<<<1, 128, 0, stream>>>(cbpart, fc1b, cbias);
    enc2_kernel<<<dim3(L, 8), 256, 0, stream>>>(x, encW, encb, hb2);
    for (int i = 0; i < NB; ++i) {
        tgen_kernel<<<1584, 256, 0, stream>>>(K + i * H * L, tfrag);
        conv3_kernel<<<dim3(H, 32), 256, 0, stream>>>(hb2, tfrag, dsk + i * H, z2);
        mix2_kernel<<<dim3(L / 2, 16), 512, 0, stream>>>(z2, hb2, wfrag + i * 18432,
                                                         boutp + i * H, lnw + i * H, lnb + i * H);
    }
    fc1m_kernel<<<dim3(42, 16), 256, 0, stream>>>(hb2, wcfrag, partial);
    fc1red_kernel<<<768, 256, 0, stream>>>(partial, cbias, t1);
    fc2_kernel<<<768, 256, 0, stream>>>(t1, fc2W, fc2b, (float*)d_out);
}

// Round 16
// 564.950 us; speedup vs baseline: 1.0943x; 1.0943x over previous
//
#include <hip/hip_runtime.h>
#include <hip/hip_bf16.h>
#include <math.h>

#define NB 4
#define B  2048
#define L  168
#define DI 9
#define H  96
#define N2 48

#define ZSTR2 132   // mix2/fc1m zs row stride (ushorts): 128 + 4 pad
#define CZ 68       // conv3 zs row stride (ushorts): 64 + 4 pad (conflict-free, verified r12)

typedef short short8 __attribute__((ext_vector_type(8)));
typedef float f32x4  __attribute__((ext_vector_type(4)));
typedef unsigned short u16x8 __attribute__((ext_vector_type(8)));
typedef unsigned short u16x4 __attribute__((ext_vector_type(4)));

// exact-algebra gelu: 0.5x(1+tanh(y)) == x*(1 - 1/(exp(2y)+1)), exp via native v_exp_f32 (2^x)
__device__ __forceinline__ float gelu_f(float x) {
    float x2 = x * x;
    float e  = __builtin_amdgcn_exp2f(x * fmaf(0.1029432225f, x2, 2.3022081899f));
    float r  = __builtin_amdgcn_rcpf(e + 1.0f);
    return x * (1.0f - r);
}

__device__ __forceinline__ unsigned short bf16_rne(float x) {
    unsigned u = __float_as_uint(x);
    return (unsigned short)((u + 0x7FFFu + ((u >> 16) & 1u)) >> 16);
}
__device__ __forceinline__ float b2f(unsigned short v) {
    return __uint_as_float((unsigned)v << 16);
}

// ---------------- S4D kernel generation: K[i][h][l] ----------------
__global__ void kgen_kernel(const float* __restrict__ log_dt, const float* __restrict__ lar,
                            const float* __restrict__ aim, const float* __restrict__ cre,
                            const float* __restrict__ cim, float* __restrict__ K)
{
    const int ih   = blockIdx.x;
    const int lane = threadIdx.x;
    float ctre = 0.f, ctim = 0.f, pre = 0.f, pim = 0.f, mre = 0.f, mim = 0.f;
    if (lane < N2) {
        float dt  = expf(log_dt[ih]);
        int   idx = ih * N2 + lane;
        float reA = -expf(lar[idx]);
        float imA = aim[idx];
        float dre = dt * reA, dim = dt * imA;
        float er  = expf(dre);
        float sv, cv;
        sincosf(dim, &sv, &cv);
        mre = er * cv; mim = er * sv;
        float nre = mre - 1.0f, nim = mim;
        float den = reA * reA + imA * imA;
        float tre = (nre * reA + nim * imA) / den;
        float tim = (nim * reA - nre * imA) / den;
        float cr = cre[idx], ci = cim[idx];
        ctre = cr * tre - ci * tim;
        ctim = cr * tim + ci * tre;
        pre = 1.0f; pim = 0.0f;
    }
    float* Kr = K + ih * L;
    for (int l = 0; l < L; ++l) {
        float term = ctre * pre - ctim * pim;
        #pragma unroll
        for (int off = 32; off > 0; off >>= 1) term += __shfl_xor(term, off, 64);
        if (lane == 0) Kr[l] = 2.0f * term;
        float nr = pre * mre - pim * mim;
        float ni = pre * mim + pim * mre;
        pre = nr; pim = ni;
    }
}

// ---------------- prepack W (layers of 96x96, row=k, col=out) into MFMA A-frags hi/lo ----------------
__global__ void wprep_kernel(const float* __restrict__ wout, short* __restrict__ wfrag, int ntask)
{
    int idx = blockIdx.x * 256 + threadIdx.x;
    if (idx >= ntask) return;
    int layer = idx / 9216;  int rem  = idx - layer * 9216;
    int ch    = rem / 3072;  int rem2 = rem - ch * 3072;
    int m     = rem2 / 512;  int rem3 = rem2 - m * 512;
    int s     = rem3 / 256;  int rem4 = rem3 - s * 256;
    int lane  = rem4 / 4;    int d    = rem4 - lane * 4;
    int g = lane >> 4, c = lane & 15;
    int k  = ch * 32 + g * 8 + 2 * d;
    int hp = m * 16 + c;
    const float* Wl = wout + (size_t)layer * H * H;
    float w0 = Wl[k * H + hp];
    float w1 = Wl[(k + 1) * H + hp];
    unsigned short b0, b1;
    if (s == 0) { b0 = bf16_rne(w0); b1 = bf16_rne(w1); }
    else {
        unsigned short h0 = bf16_rne(w0), h1 = bf16_rne(w1);
        b0 = bf16_rne(w0 - b2f(h0));
        b1 = bf16_rne(w1 - b2f(h1));
    }
    wfrag[idx * 2]     = (short)b0;
    wfrag[idx * 2 + 1] = (short)b1;
}

// ---------------- Toeplitz A-fragments (hi-only bf16): T[l][l'] = K[l-l'] ----------------
__global__ void tgen_kernel(const float* __restrict__ Kg, short* __restrict__ tfrag)
{
    static const int kmaxA[11] = {0, 0, 1, 1, 2, 2, 3, 3, 4, 4, 5};
    static const int toffA[11] = {0, 1, 2, 4, 6, 9, 12, 16, 20, 25, 30};
    int idx = blockIdx.x * 256 + threadIdx.x;          // 96*66*64 tasks
    if (idx >= 96 * 66 * 64) return;
    int lane = idx & 63;
    int t    = (idx >> 6) % 66;
    int h    = (idx >> 6) / 66;
    int mi = t / 6, ki = t - mi * 6;
    if (ki > kmaxA[mi]) return;
    int g = lane >> 4, c = lane & 15;
    int row = mi * 16 + c;
    short8 a;
    #pragma unroll
    for (int j = 0; j < 8; ++j) {
        int kk = ki * 32 + g * 8 + j;
        int d  = row - kk;
        float val = (row < L && d >= 0) ? Kg[h * L + d] : 0.0f;
        a[j] = (short)bf16_rne(val);
    }
    short8* dst = (short8*)tfrag + (size_t)(h * 36 + toffA[mi] + ki) * 64;
    dst[lane] = a;
}

// ---------------- compose decW into fc1W ----------------
__launch_bounds__(256)
__global__ void wcomp_kernel(const float* __restrict__ decW, const float* __restrict__ decb,
                             const float* __restrict__ fc1W, float* __restrict__ wcs,
                             float* __restrict__ cbpart)
{
    __shared__ float Bs[96 * 100];
    const int tid = threadIdx.x;
    const int l   = blockIdx.x;
    for (int e = tid; e < 96 * 96; e += 256) {
        int h = e / 96, p = e - h * 96;
        Bs[h * 100 + p] = fc1W[(size_t)(l * 96 + h) * 96 + p];
    }
    __syncthreads();
    const int pt = tid & 31;
    const int kt = tid >> 5;
    float acc[12][3];
    #pragma unroll
    for (int kk = 0; kk < 12; ++kk)
        #pragma unroll
        for (int j = 0; j < 3; ++j) acc[kk][j] = 0.f;
    for (int h = 0; h < 96; ++h) {
        float dw[12];
        #pragma unroll
        for (int kk = 0; kk < 12; ++kk) dw[kk] = decW[(kt + 8 * kk) * 96 + h];
        float bs[3];
        #pragma unroll
        for (int j = 0; j < 3; ++j) bs[j] = Bs[h * 100 + pt + 32 * j];
        #pragma unroll
        for (int kk = 0; kk < 12; ++kk)
            #pragma unroll
            for (int j = 0; j < 3; ++j) acc[kk][j] = fmaf(dw[kk], bs[j], acc[kk][j]);
    }
    float* wl = wcs + (size_t)l * 9216;
    #pragma unroll
    for (int kk = 0; kk < 12; ++kk)
        #pragma unroll
        for (int j = 0; j < 3; ++j)
            wl[(kt + 8 * kk) * 96 + pt + 32 * j] = acc[kk][j];
    if (kt == 0) {
        #pragma unroll
        for (int j = 0; j < 3; ++j) {
            float s = 0.f;
            for (int h = 0; h < 96; ++h) s = fmaf(decb[h], Bs[h * 100 + pt + 32 * j], s);
            cbpart[l * 96 + pt + 32 * j] = s;
        }
    }
}

__global__ void cbias_red_kernel(const float* __restrict__ cbpart, const float* __restrict__ fc1b,
                                 float* __restrict__ cbias)
{
    int p = threadIdx.x;
    if (p < 96) {
        float s = fc1b[p];
        for (int l = 0; l < L; ++l) s += cbpart[l * 96 + p];
        cbias[p] = s;
    }
}

// ---------------- encoder into (h,l,b) bf16 ----------------
__launch_bounds__(256)
__global__ void enc2_kernel(const float* __restrict__ x, const float* __restrict__ W,
                            const float* __restrict__ bias, unsigned short* __restrict__ hb2)
{
    __shared__ float Ws[DI * H];
    __shared__ float bs[H];
    const int tid = threadIdx.x;
    const int l   = blockIdx.x;
    const int b0  = blockIdx.y * 256;
    for (int e = tid; e < DI * H; e += 256) Ws[e] = W[e];
    if (tid < H) bs[tid] = bias[tid];
    __syncthreads();
    float xv[DI];
    const float* xr = x + (size_t)(b0 + tid) * (L * DI) + l * DI;
    #pragma unroll
    for (int k = 0; k < DI; ++k) xv[k] = xr[k];
    for (int h = 0; h < H; ++h) {
        float a = bs[h];
        #pragma unroll
        for (int k = 0; k < DI; ++k) a = fmaf(xv[k], Ws[k * H + h], a);
        hb2[((size_t)h * L + l) * B + b0 + tid] = bf16_rne(a);
    }
}

// ---------------- conv via Toeplitz MFMA + skip + GELU: chunk 64, batched Tf loads ----------------
__launch_bounds__(256, 4)
__global__ void conv3_kernel(const unsigned short* __restrict__ hb2, const short* __restrict__ tfrag,
                             const float* __restrict__ Dsk, unsigned short* __restrict__ z2)
{
    static const int toffA[11] = {0, 1, 2, 4, 6, 9, 12, 16, 20, 25, 30};
    __shared__ __align__(16) unsigned short zs[192 * CZ];   // 26.1 KB
    const int tid  = threadIdx.x;
    const int w    = tid >> 6;
    const int lane = tid & 63;
    const int g    = lane >> 4;
    const int cc   = lane & 15;
    const int h    = blockIdx.x;
    const int b0   = blockIdx.y * 64;

    for (int e = tid; e < 168 * 8; e += 256) {
        int lp = e >> 3, b8 = e & 7;
        u16x8 v = *(const u16x8*)(hb2 + ((size_t)h * L + lp) * B + b0 + b8 * 8);
        *(u16x4*)(&zs[lp * CZ + b8 * 8])     = (u16x4){v[0], v[1], v[2], v[3]};
        *(u16x4*)(&zs[lp * CZ + b8 * 8 + 4]) = (u16x4){v[4], v[5], v[6], v[7]};
    }
    for (int e = tid; e < 24 * 8; e += 256) {
        int lp = 168 + (e >> 3), b8 = e & 7;
        *(u16x4*)(&zs[lp * CZ + b8 * 8])     = (u16x4){0, 0, 0, 0};
        *(u16x4*)(&zs[lp * CZ + b8 * 8 + 4]) = (u16x4){0, 0, 0, 0};
    }
    __syncthreads();

    f32x4 acc[11];
    #pragma unroll
    for (int mi = 0; mi < 11; ++mi) acc[mi] = (f32x4){0.f, 0.f, 0.f, 0.f};

    const int col = w * 16 + cc;
    const short8* Tbase = (const short8*)tfrag + (size_t)h * 36 * 64 + lane;

    #pragma unroll
    for (int ki = 0; ki < 6; ++ki) {
        short8 bh;
        #pragma unroll
        for (int j = 0; j < 8; ++j)
            bh[j] = (short)zs[(ki * 32 + g * 8 + j) * CZ + col];
        short8 tf[11];
        #pragma unroll
        for (int mi = 0; mi < 11; ++mi)
            if (mi >= 2 * ki)
                tf[mi] = Tbase[(size_t)(toffA[mi] + ki) * 64];
        #pragma unroll
        for (int mi = 0; mi < 11; ++mi)
            if (mi >= 2 * ki)
                acc[mi] = __builtin_amdgcn_mfma_f32_16x16x32_bf16(tf[mi], bh, acc[mi], 0, 0, 0);
    }

    const float ds = Dsk[h];
    #pragma unroll
    for (int mi = 0; mi < 11; ++mi) {
        #pragma unroll
        for (int r = 0; r < 4; ++r) {
            int l = mi * 16 + g * 4 + r;
            if (l < L) {
                float uu = b2f(zs[l * CZ + col]);
                float zv = gelu_f(fmaf(ds, uu, acc[mi][r]));
                zs[l * CZ + col] = bf16_rne(zv);
            }
        }
    }
    __syncthreads();
    for (int e = tid; e < 168 * 8; e += 256) {
        int lp = e >> 3, b8 = e & 7;
        u16x4 a = *(const u16x4*)(&zs[lp * CZ + b8 * 8]);
        u16x4 b = *(const u16x4*)(&zs[lp * CZ + b8 * 8 + 4]);
        u16x8 v = {a[0], a[1], a[2], a[3], b[0], b[1], b[2], b[3]};
        *(u16x8*)(z2 + ((size_t)h * L + lp) * B + b0 + b8 * 8) = v;
    }
}

// ---------------- W_out GEMM + bias + residual + LN: 8 waves, single time-shared LDS buffer ----------------
__launch_bounds__(512)
__global__ void mix2_kernel(const unsigned short* __restrict__ z2, unsigned short* __restrict__ hb2,
                            const short* __restrict__ wfrag, const float* __restrict__ bout,
                            const float* __restrict__ lnw, const float* __restrict__ lnb)
{
    __shared__ __align__(16) unsigned short zs[H * ZSTR2];   // 25.3 KB: z, then residual, then LN out
    const int tid  = threadIdx.x;
    const int w    = tid >> 6;          // 0..7, one 16-col n-tile each
    const int lane = tid & 63;
    const int g    = lane >> 4;
    const int cc   = lane & 15;
    const int l    = blockIdx.x;
    const int b0   = blockIdx.y * 128;

    // phase 1: stage z
    for (int e = tid; e < 96 * 16; e += 512) {
        int hh = e >> 4, b8 = e & 15;
        u16x8 v = *(const u16x8*)(z2 + ((size_t)hh * L + l) * B + b0 + b8 * 8);
        *(u16x4*)(&zs[hh * ZSTR2 + b8 * 8])     = (u16x4){v[0], v[1], v[2], v[3]};
        *(u16x4*)(&zs[hh * ZSTR2 + b8 * 8 + 4]) = (u16x4){v[4], v[5], v[6], v[7]};
    }
    __syncthreads();

    // phase 2: MFMA
    f32x4 acc[6];
    #pragma unroll
    for (int m = 0; m < 6; ++m) acc[m] = (f32x4){0.f, 0.f, 0.f, 0.f};

    const int col = w * 16 + cc;

    #pragma unroll
    for (int ks = 0; ks < 3; ++ks) {
        short8 bh;
        #pragma unroll
        for (int j = 0; j < 8; ++j)
            bh[j] = (short)zs[(ks * 32 + g * 8 + j) * ZSTR2 + col];
        const short8* Wf = (const short8*)(wfrag) + ks * 12 * 64;
        short8 wa[12];
        #pragma unroll
        for (int m = 0; m < 12; ++m) wa[m] = Wf[m * 64 + lane];
        #pragma unroll
        for (int m = 0; m < 6; ++m) {
            acc[m] = __builtin_amdgcn_mfma_f32_16x16x32_bf16(wa[2 * m + 1], bh, acc[m], 0, 0, 0);
            acc[m] = __builtin_amdgcn_mfma_f32_16x16x32_bf16(wa[2 * m],     bh, acc[m], 0, 0, 0);
        }
    }
    __syncthreads();   // all MFMA LDS reads retired

    // phase 3: stage residual into the SAME buffer
    for (int e = tid; e < 96 * 16; e += 512) {
        int hh = e >> 4, b8 = e & 15;
        u16x8 v = *(const u16x8*)(hb2 + ((size_t)hh * L + l) * B + b0 + b8 * 8);
        *(u16x4*)(&zs[hh * ZSTR2 + b8 * 8])     = (u16x4){v[0], v[1], v[2], v[3]};
        *(u16x4*)(&zs[hh * ZSTR2 + b8 * 8 + 4]) = (u16x4){v[4], v[5], v[6], v[7]};
    }
    __syncthreads();

    // phase 4: epilogue — +bias +residual, LN over h', write back in place (cols wave-partitioned)
    float vals[6][4];
    float s = 0.f, q = 0.f;
    #pragma unroll
    for (int m = 0; m < 6; ++m) {
        float4 B4 = *(const float4*)(bout + m * 16 + g * 4);
        float bo[4] = {B4.x, B4.y, B4.z, B4.w};
        #pragma unroll
        for (int r = 0; r < 4; ++r) {
            int hr = m * 16 + g * 4 + r;
            float res = b2f(zs[hr * ZSTR2 + col]);
            float v = acc[m][r] + bo[r] + res;
            vals[m][r] = v;
            s += v; q += v * v;
        }
    }
    s += __shfl_xor(s, 16, 64); q += __shfl_xor(q, 16, 64);
    s += __shfl_xor(s, 32, 64); q += __shfl_xor(q, 32, 64);
    float mean = s * (1.0f / 96.0f);
    float var  = q * (1.0f / 96.0f) - mean * mean;
    float rstd = rsqrtf(var + 1e-5f);
    #pragma unroll
    for (int m = 0; m < 6; ++m) {
        float4 W4 = *(const float4*)(lnw + m * 16 + g * 4);
        float4 Bb = *(const float4*)(lnb + m * 16 + g * 4);
        float wv[4] = {W4.x, W4.y, W4.z, W4.w};
        float bv[4] = {Bb.x, Bb.y, Bb.z, Bb.w};
        #pragma unroll
        for (int r = 0; r < 4; ++r) {
            int hr = m * 16 + g * 4 + r;
            zs[hr * ZSTR2 + col] = bf16_rne(fmaf((vals[m][r] - mean) * rstd, wv[r], bv[r]));
        }
    }
    __syncthreads();

    // phase 5: coalesced store
    for (int e = tid; e < 96 * 16; e += 512) {
        int hh = e >> 4, b8 = e & 15;
        u16x4 a = *(const u16x4*)(&zs[hh * ZSTR2 + b8 * 8]);
        u16x4 b = *(const u16x4*)(&zs[hh * ZSTR2 + b8 * 8 + 4]);
        u16x8 v = {a[0], a[1], a[2], a[3], b[0], b[1], b[2], b[3]};
        *(u16x8*)(hb2 + ((size_t)hh * L + l) * B + b0 + b8 * 8) = v;
    }
}

// ---------------- fc1 via MFMA with composed dec+fc1 weights, split-K over 42 ----------------
__launch_bounds__(256)
__global__ void fc1m_kernel(const unsigned short* __restrict__ hb2, const short* __restrict__ wcfrag,
                            float* __restrict__ partial)
{
    __shared__ __align__(16) unsigned short zs[H * ZSTR2];
    const int tid  = threadIdx.x;
    const int w    = tid >> 6;
    const int lane = tid & 63;
    const int g    = lane >> 4;
    const int cc   = lane & 15;
    const int ksp  = blockIdx.x;
    const int b0   = blockIdx.y * 128;

    f32x4 acc[2][6];
    #pragma unroll
    for (int n2 = 0; n2 < 2; ++n2)
        #pragma unroll
        for (int m = 0; m < 6; ++m) acc[n2][m] = (f32x4){0.f, 0.f, 0.f, 0.f};

    for (int il = 0; il < 4; ++il) {
        const int l = ksp * 4 + il;
        __syncthreads();
        for (int e = tid; e < 96 * 16; e += 256) {
            int hh = e >> 4, b8 = e & 15;
            u16x8 v = *(const u16x8*)(hb2 + ((size_t)hh * L + l) * B + b0 + b8 * 8);
            *(u16x4*)(&zs[hh * ZSTR2 + b8 * 8])     = (u16x4){v[0], v[1], v[2], v[3]};
            *(u16x4*)(&zs[hh * ZSTR2 + b8 * 8 + 4]) = (u16x4){v[4], v[5], v[6], v[7]};
        }
        __syncthreads();
        for (int ksl = 0; ksl < 3; ++ksl) {
            short8 bh[2];
            #pragma unroll
            for (int n2 = 0; n2 < 2; ++n2) {
                int col = (w * 2 + n2) * 16 + cc;
                #pragma unroll
                for (int j = 0; j < 8; ++j)
                    bh[n2][j] = (short)zs[(ksl * 32 + g * 8 + j) * ZSTR2 + col];
            }
            const short8* Wf = (const short8*)(wcfrag) + (size_t)(l * 3 + ksl) * 768;
            short8 wa[12];
            #pragma unroll
            for (int m = 0; m < 12; ++m) wa[m] = Wf[m * 64 + lane];
            #pragma unroll
            for (int m = 0; m < 6; ++m) {
                #pragma unroll
                for (int n2 = 0; n2 < 2; ++n2) {
                    acc[n2][m] = __builtin_amdgcn_mfma_f32_16x16x32_bf16(wa[2 * m + 1], bh[n2], acc[n2][m], 0, 0, 0);
                    acc[n2][m] = __builtin_amdgcn_mfma_f32_16x16x32_bf16(wa[2 * m],     bh[n2], acc[n2][m], 0, 0, 0);
                }
            }
        }
    }

    #pragma unroll
    for (int n2 = 0; n2 < 2; ++n2) {
        int gb = b0 + (w * 2 + n2) * 16 + cc;
        #pragma unroll
        for (int m = 0; m < 6; ++m) {
            *(float4*)&partial[((size_t)ksp * B + gb) * 96 + m * 16 + g * 4] =
                make_float4(acc[n2][m][0], acc[n2][m][1], acc[n2][m][2], acc[n2][m][3]);
        }
    }
}

__global__ void fc1red_kernel(const float* __restrict__ partial, const float* __restrict__ cbias,
                              float* __restrict__ t1)
{
    int o = blockIdx.x * 256 + threadIdx.x;
    int p = o % 96;
    float s = cbias[p];
    #pragma unroll 6
    for (int k = 0; k < 42; ++k) s += partial[(size_t)k * (B * 96) + o];
    t1[o] = s;
}

__launch_bounds__(256)
__global__ void fc2_kernel(const float* __restrict__ t1, const float* __restrict__ W,
                           const float* __restrict__ fb, float* __restrict__ out)
{
    __shared__ float Ws[96 * 100];
    const int tid = threadIdx.x;
    for (int e = tid; e < 96 * 96; e += 256) Ws[(e / 96) * 100 + (e % 96)] = W[e];
    __syncthreads();
    int o = blockIdx.x * 256 + tid;
    int b = o / 96, p = o - b * 96;
    const float* tr = t1 + b * 96;
    float acc = fb[p];
    #pragma unroll 4
    for (int h = 0; h < 96; ++h) acc = fmaf(tr[h], Ws[h * 100 + p], acc);
    out[o] = acc;
}

extern "C" void kernel_launch(void* const* d_in, const int* in_sizes, int n_in,
                              void* d_out, int out_size, void* d_ws, size_t ws_size,
                              hipStream_t stream)
{
    const float* x      = (const float*)d_in[0];
    const float* encW   = (const float*)d_in[1];
    const float* encb   = (const float*)d_in[2];
    const float* log_dt = (const float*)d_in[3];
    const float* lar    = (const float*)d_in[4];
    const float* aim    = (const float*)d_in[5];
    const float* cre    = (const float*)d_in[6];
    const float* cim    = (const float*)d_in[7];
    const float* dsk    = (const float*)d_in[8];
    const float* wout   = (const float*)d_in[9];
    const float* boutp  = (const float*)d_in[10];
    const float* lnw    = (const float*)d_in[11];
    const float* lnb    = (const float*)d_in[12];
    const float* decW   = (const float*)d_in[13];
    const float* decb   = (const float*)d_in[14];
    const float* fc1W   = (const float*)d_in[15];
    const float* fc1b   = (const float*)d_in[16];
    const float* fc2W   = (const float*)d_in[17];
    const float* fc2b   = (const float*)d_in[18];

    // ws layout (max end = 143 MiB, proven envelope):
    char*           ws      = (char*)d_ws;
    float*          K       = (float*)(ws);                              // 258 KB
    short*          wfrag   = (short*)(ws + ((size_t)384 << 10));        // 147 KB
    float*          t1      = (float*)(ws + ((size_t)1 << 20));          // 786 KB
    float*          cbpart  = (float*)(ws + ((size_t)1 << 20) + (900 << 10)); // 64.5 KB
    float*          cbias   = (float*)(ws + ((size_t)1 << 20) + (980 << 10)); // 384 B
    short*          wcfrag  = (short*)(ws + ((size_t)2 << 20));          // 6.19 MB
    short*          tfrag   = (short*)(ws + ((size_t)9 << 20));          // 3.38 MB (hi-only)
    float*          wcs     = (float*)(ws + ((size_t)9 << 20));          // 6.19 MB, dead before tgen (alias)
    unsigned short* hb2     = (unsigned short*)(ws + ((size_t)16 << 20)); // 63.0 MiB (h,l,b) bf16
    unsigned short* z2      = (unsigned short*)(ws + ((size_t)80 << 20)); // 63.0 MiB (h,l,b) bf16
    float*          partial = (float*)(ws + ((size_t)80 << 20));          // 33 MiB, aliases z2

    kgen_kernel<<<NB * H, 64, 0, stream>>>(log_dt, lar, aim, cre, cim, K);
    wprep_kernel<<<144, 256, 0, stream>>>(wout, wfrag, NB * 9216);
    wcomp_kernel<<<L, 256, 0, stream>>>(decW, decb, fc1W, wcs, cbpart);
    wprep_kernel<<<6048, 256, 0, stream>>>(wcs, wcfrag, L * 9216);
    cbias_red_kernel<<<1, 128, 0, stream>>>(cbpart, fc1b, cbias);
    enc2_kernel<<<dim3(L, 8), 256, 0, stream>>>(x, encW, encb, hb2);
    for (int i = 0; i < NB; ++i) {
        tgen_kernel<<<1584, 256, 0, stream>>>(K + i * H * L, tfrag);
        conv3_kernel<<<dim3(H, 32), 256, 0, stream>>>(hb2, tfrag, dsk + i * H, z2);
        mix2_kernel<<<dim3(L, 16), 512, 0, stream>>>(z2, hb2, wfrag + i * 18432,
                                                     boutp + i * H, lnw + i * H, lnb + i * H);
    }
    fc1m_kernel<<<dim3(42, 16), 256, 0, stream>>>(hb2, wcfrag, partial);
    fc1red_kernel<<<768, 256, 0, stream>>>(partial, cbias, t1);
    fc2_kernel<<<768, 256, 0, stream>>>(t1, fc2W, fc2b, (float*)d_out);
}

// Round 17
// 489.220 us; speedup vs baseline: 1.2637x; 1.1548x over previous
//
#include <hip/hip_runtime.h>
#include <hip/hip_bf16.h>
#include <math.h>

#define NB 4
#define B  2048
#define L  168
#define DI 9
#define H  96
#define N2 48

#define ZSTR2 132   // mix2/fc1m zs row stride (ushorts): 128 + 4 pad
#define CZ 68       // conv3 zs row stride (ushorts): 64 + 4 pad (conflict-free, verified r12)

typedef short short8 __attribute__((ext_vector_type(8)));
typedef float f32x4  __attribute__((ext_vector_type(4)));
typedef unsigned short u16x8 __attribute__((ext_vector_type(8)));
typedef unsigned short u16x4 __attribute__((ext_vector_type(4)));

// exact-algebra gelu: 0.5x(1+tanh(y)) == x*(1 - 1/(exp(2y)+1)), exp via native v_exp_f32 (2^x)
__device__ __forceinline__ float gelu_f(float x) {
    float x2 = x * x;
    float e  = __builtin_amdgcn_exp2f(x * fmaf(0.1029432225f, x2, 2.3022081899f));
    float r  = __builtin_amdgcn_rcpf(e + 1.0f);
    return x * (1.0f - r);
}

__device__ __forceinline__ unsigned short bf16_rne(float x) {
    unsigned u = __float_as_uint(x);
    return (unsigned short)((u + 0x7FFFu + ((u >> 16) & 1u)) >> 16);
}
__device__ __forceinline__ float b2f(unsigned short v) {
    return __uint_as_float((unsigned)v << 16);
}

// ---------------- S4D kernel generation: K[i][h][l] ----------------
__global__ void kgen_kernel(const float* __restrict__ log_dt, const float* __restrict__ lar,
                            const float* __restrict__ aim, const float* __restrict__ cre,
                            const float* __restrict__ cim, float* __restrict__ K)
{
    const int ih   = blockIdx.x;
    const int lane = threadIdx.x;
    float ctre = 0.f, ctim = 0.f, pre = 0.f, pim = 0.f, mre = 0.f, mim = 0.f;
    if (lane < N2) {
        float dt  = expf(log_dt[ih]);
        int   idx = ih * N2 + lane;
        float reA = -expf(lar[idx]);
        float imA = aim[idx];
        float dre = dt * reA, dim = dt * imA;
        float er  = expf(dre);
        float sv, cv;
        sincosf(dim, &sv, &cv);
        mre = er * cv; mim = er * sv;
        float nre = mre - 1.0f, nim = mim;
        float den = reA * reA + imA * imA;
        float tre = (nre * reA + nim * imA) / den;
        float tim = (nim * reA - nre * imA) / den;
        float cr = cre[idx], ci = cim[idx];
        ctre = cr * tre - ci * tim;
        ctim = cr * tim + ci * tre;
        pre = 1.0f; pim = 0.0f;
    }
    float* Kr = K + ih * L;
    for (int l = 0; l < L; ++l) {
        float term = ctre * pre - ctim * pim;
        #pragma unroll
        for (int off = 32; off > 0; off >>= 1) term += __shfl_xor(term, off, 64);
        if (lane == 0) Kr[l] = 2.0f * term;
        float nr = pre * mre - pim * mim;
        float ni = pre * mim + pim * mre;
        pre = nr; pim = ni;
    }
}

// ---------------- prepack W (layers of 96x96, row=k, col=out) into MFMA A-frags hi/lo ----------------
__global__ void wprep_kernel(const float* __restrict__ wout, short* __restrict__ wfrag, int ntask)
{
    int idx = blockIdx.x * 256 + threadIdx.x;
    if (idx >= ntask) return;
    int layer = idx / 9216;  int rem  = idx - layer * 9216;
    int ch    = rem / 3072;  int rem2 = rem - ch * 3072;
    int m     = rem2 / 512;  int rem3 = rem2 - m * 512;
    int s     = rem3 / 256;  int rem4 = rem3 - s * 256;
    int lane  = rem4 / 4;    int d    = rem4 - lane * 4;
    int g = lane >> 4, c = lane & 15;
    int k  = ch * 32 + g * 8 + 2 * d;
    int hp = m * 16 + c;
    const float* Wl = wout + (size_t)layer * H * H;
    float w0 = Wl[k * H + hp];
    float w1 = Wl[(k + 1) * H + hp];
    unsigned short b0, b1;
    if (s == 0) { b0 = bf16_rne(w0); b1 = bf16_rne(w1); }
    else {
        unsigned short h0 = bf16_rne(w0), h1 = bf16_rne(w1);
        b0 = bf16_rne(w0 - b2f(h0));
        b1 = bf16_rne(w1 - b2f(h1));
    }
    wfrag[idx * 2]     = (short)b0;
    wfrag[idx * 2 + 1] = (short)b1;
}

// ---------------- Toeplitz A-fragments (hi-only bf16): T[l][l'] = K[l-l'] ----------------
__global__ void tgen_kernel(const float* __restrict__ Kg, short* __restrict__ tfrag)
{
    static const int kmaxA[11] = {0, 0, 1, 1, 2, 2, 3, 3, 4, 4, 5};
    static const int toffA[11] = {0, 1, 2, 4, 6, 9, 12, 16, 20, 25, 30};
    int idx = blockIdx.x * 256 + threadIdx.x;          // 96*66*64 tasks
    if (idx >= 96 * 66 * 64) return;
    int lane = idx & 63;
    int t    = (idx >> 6) % 66;
    int h    = (idx >> 6) / 66;
    int mi = t / 6, ki = t - mi * 6;
    if (ki > kmaxA[mi]) return;
    int g = lane >> 4, c = lane & 15;
    int row = mi * 16 + c;
    short8 a;
    #pragma unroll
    for (int j = 0; j < 8; ++j) {
        int kk = ki * 32 + g * 8 + j;
        int d  = row - kk;
        float val = (row < L && d >= 0) ? Kg[h * L + d] : 0.0f;
        a[j] = (short)bf16_rne(val);
    }
    short8* dst = (short8*)tfrag + (size_t)(h * 36 + toffA[mi] + ki) * 64;
    dst[lane] = a;
}

// ---------------- compose decW into fc1W ----------------
__launch_bounds__(256)
__global__ void wcomp_kernel(const float* __restrict__ decW, const float* __restrict__ decb,
                             const float* __restrict__ fc1W, float* __restrict__ wcs,
                             float* __restrict__ cbpart)
{
    __shared__ float Bs[96 * 100];
    const int tid = threadIdx.x;
    const int l   = blockIdx.x;
    for (int e = tid; e < 96 * 96; e += 256) {
        int h = e / 96, p = e - h * 96;
        Bs[h * 100 + p] = fc1W[(size_t)(l * 96 + h) * 96 + p];
    }
    __syncthreads();
    const int pt = tid & 31;
    const int kt = tid >> 5;
    float acc[12][3];
    #pragma unroll
    for (int kk = 0; kk < 12; ++kk)
        #pragma unroll
        for (int j = 0; j < 3; ++j) acc[kk][j] = 0.f;
    for (int h = 0; h < 96; ++h) {
        float dw[12];
        #pragma unroll
        for (int kk = 0; kk < 12; ++kk) dw[kk] = decW[(kt + 8 * kk) * 96 + h];
        float bs[3];
        #pragma unroll
        for (int j = 0; j < 3; ++j) bs[j] = Bs[h * 100 + pt + 32 * j];
        #pragma unroll
        for (int kk = 0; kk < 12; ++kk)
            #pragma unroll
            for (int j = 0; j < 3; ++j) acc[kk][j] = fmaf(dw[kk], bs[j], acc[kk][j]);
    }
    float* wl = wcs + (size_t)l * 9216;
    #pragma unroll
    for (int kk = 0; kk < 12; ++kk)
        #pragma unroll
        for (int j = 0; j < 3; ++j)
            wl[(kt + 8 * kk) * 96 + pt + 32 * j] = acc[kk][j];
    if (kt == 0) {
        #pragma unroll
        for (int j = 0; j < 3; ++j) {
            float s = 0.f;
            for (int h = 0; h < 96; ++h) s = fmaf(decb[h], Bs[h * 100 + pt + 32 * j], s);
            cbpart[l * 96 + pt + 32 * j] = s;
        }
    }
}

__global__ void cbias_red_kernel(const float* __restrict__ cbpart, const float* __restrict__ fc1b,
                                 float* __restrict__ cbias)
{
    int p = threadIdx.x;
    if (p < 96) {
        float s = fc1b[p];
        for (int l = 0; l < L; ++l) s += cbpart[l * 96 + p];
        cbias[p] = s;
    }
}

// ---------------- encoder into (h,l,b) bf16 ----------------
__launch_bounds__(256)
__global__ void enc2_kernel(const float* __restrict__ x, const float* __restrict__ W,
                            const float* __restrict__ bias, unsigned short* __restrict__ hb2)
{
    __shared__ float Ws[DI * H];
    __shared__ float bs[H];
    const int tid = threadIdx.x;
    const int l   = blockIdx.x;
    const int b0  = blockIdx.y * 256;
    for (int e = tid; e < DI * H; e += 256) Ws[e] = W[e];
    if (tid < H) bs[tid] = bias[tid];
    __syncthreads();
    float xv[DI];
    const float* xr = x + (size_t)(b0 + tid) * (L * DI) + l * DI;
    #pragma unroll
    for (int k = 0; k < DI; ++k) xv[k] = xr[k];
    for (int h = 0; h < H; ++h) {
        float a = bs[h];
        #pragma unroll
        for (int k = 0; k < DI; ++k) a = fmaf(xv[k], Ws[k * H + h], a);
        hb2[((size_t)h * L + l) * B + b0 + tid] = bf16_rne(a);
    }
}

// ---------------- conv via Toeplitz MFMA + skip + GELU: chunk 64, batched Tf loads ----------------
// grid: x = b-chunk (32), y = h (96) -> consecutive blocks read adjacent 128B chunks of same rows
__launch_bounds__(256, 4)
__global__ void conv3_kernel(const unsigned short* __restrict__ hb2, const short* __restrict__ tfrag,
                             const float* __restrict__ Dsk, unsigned short* __restrict__ z2)
{
    static const int toffA[11] = {0, 1, 2, 4, 6, 9, 12, 16, 20, 25, 30};
    __shared__ __align__(16) unsigned short zs[192 * CZ];   // 26.1 KB
    const int tid  = threadIdx.x;
    const int w    = tid >> 6;
    const int lane = tid & 63;
    const int g    = lane >> 4;
    const int cc   = lane & 15;
    const int h    = blockIdx.y;
    const int b0   = blockIdx.x * 64;

    for (int e = tid; e < 168 * 8; e += 256) {
        int lp = e >> 3, b8 = e & 7;
        u16x8 v = *(const u16x8*)(hb2 + ((size_t)h * L + lp) * B + b0 + b8 * 8);
        *(u16x4*)(&zs[lp * CZ + b8 * 8])     = (u16x4){v[0], v[1], v[2], v[3]};
        *(u16x4*)(&zs[lp * CZ + b8 * 8 + 4]) = (u16x4){v[4], v[5], v[6], v[7]};
    }
    for (int e = tid; e < 24 * 8; e += 256) {
        int lp = 168 + (e >> 3), b8 = e & 7;
        *(u16x4*)(&zs[lp * CZ + b8 * 8])     = (u16x4){0, 0, 0, 0};
        *(u16x4*)(&zs[lp * CZ + b8 * 8 + 4]) = (u16x4){0, 0, 0, 0};
    }
    __syncthreads();

    f32x4 acc[11];
    #pragma unroll
    for (int mi = 0; mi < 11; ++mi) acc[mi] = (f32x4){0.f, 0.f, 0.f, 0.f};

    const int col = w * 16 + cc;
    const short8* Tbase = (const short8*)tfrag + (size_t)h * 36 * 64 + lane;

    #pragma unroll
    for (int ki = 0; ki < 6; ++ki) {
        short8 bh;
        #pragma unroll
        for (int j = 0; j < 8; ++j)
            bh[j] = (short)zs[(ki * 32 + g * 8 + j) * CZ + col];
        short8 tf[11];
        #pragma unroll
        for (int mi = 0; mi < 11; ++mi)
            if (mi >= 2 * ki)
                tf[mi] = Tbase[(size_t)(toffA[mi] + ki) * 64];
        #pragma unroll
        for (int mi = 0; mi < 11; ++mi)
            if (mi >= 2 * ki)
                acc[mi] = __builtin_amdgcn_mfma_f32_16x16x32_bf16(tf[mi], bh, acc[mi], 0, 0, 0);
    }

    const float ds = Dsk[h];
    #pragma unroll
    for (int mi = 0; mi < 11; ++mi) {
        #pragma unroll
        for (int r = 0; r < 4; ++r) {
            int l = mi * 16 + g * 4 + r;
            if (l < L) {
                float uu = b2f(zs[l * CZ + col]);
                float zv = gelu_f(fmaf(ds, uu, acc[mi][r]));
                zs[l * CZ + col] = bf16_rne(zv);
            }
        }
    }
    __syncthreads();
    for (int e = tid; e < 168 * 8; e += 256) {
        int lp = e >> 3, b8 = e & 7;
        u16x4 a = *(const u16x4*)(&zs[lp * CZ + b8 * 8]);
        u16x4 b = *(const u16x4*)(&zs[lp * CZ + b8 * 8 + 4]);
        u16x8 v = {a[0], a[1], a[2], a[3], b[0], b[1], b[2], b[3]};
        *(u16x8*)(z2 + ((size_t)h * L + lp) * B + b0 + b8 * 8) = v;
    }
}

// ---------------- W_out GEMM (hi-only W) + bias + residual + LN: 8 waves, dual-buffer (r14) ----------------
// grid: x = b-chunk (16), y = l (168)
__launch_bounds__(512)
__global__ void mix2_kernel(const unsigned short* __restrict__ z2, unsigned short* __restrict__ hb2,
                            const short* __restrict__ wfrag, const float* __restrict__ bout,
                            const float* __restrict__ lnw, const float* __restrict__ lnb)
{
    __shared__ __align__(16) unsigned short zs[H * ZSTR2];   // z (MFMA B operand)
    __shared__ __align__(16) unsigned short rs[H * ZSTR2];   // residual in, LN output out
    const int tid  = threadIdx.x;
    const int w    = tid >> 6;
    const int lane = tid & 63;
    const int g    = lane >> 4;
    const int cc   = lane & 15;
    const int l    = blockIdx.y;
    const int b0   = blockIdx.x * 128;

    for (int e = tid; e < 96 * 16; e += 512) {
        int hh = e >> 4, b8 = e & 15;
        u16x8 v = *(const u16x8*)(z2 + ((size_t)hh * L + l) * B + b0 + b8 * 8);
        *(u16x4*)(&zs[hh * ZSTR2 + b8 * 8])     = (u16x4){v[0], v[1], v[2], v[3]};
        *(u16x4*)(&zs[hh * ZSTR2 + b8 * 8 + 4]) = (u16x4){v[4], v[5], v[6], v[7]};
    }
    for (int e = tid; e < 96 * 16; e += 512) {
        int hh = e >> 4, b8 = e & 15;
        u16x8 v = *(const u16x8*)(hb2 + ((size_t)hh * L + l) * B + b0 + b8 * 8);
        *(u16x4*)(&rs[hh * ZSTR2 + b8 * 8])     = (u16x4){v[0], v[1], v[2], v[3]};
        *(u16x4*)(&rs[hh * ZSTR2 + b8 * 8 + 4]) = (u16x4){v[4], v[5], v[6], v[7]};
    }
    __syncthreads();

    f32x4 acc[6];
    #pragma unroll
    for (int m = 0; m < 6; ++m) acc[m] = (f32x4){0.f, 0.f, 0.f, 0.f};

    const int col = w * 16 + cc;

    #pragma unroll
    for (int ks = 0; ks < 3; ++ks) {
        short8 bh;
        #pragma unroll
        for (int j = 0; j < 8; ++j)
            bh[j] = (short)zs[(ks * 32 + g * 8 + j) * ZSTR2 + col];
        const short8* Wf = (const short8*)(wfrag) + ks * 12 * 64;
        // hi-only A-frags: 6 loads, 6 MFMAs
        short8 wa[6];
        #pragma unroll
        for (int m = 0; m < 6; ++m) wa[m] = Wf[(2 * m) * 64 + lane];
        #pragma unroll
        for (int m = 0; m < 6; ++m)
            acc[m] = __builtin_amdgcn_mfma_f32_16x16x32_bf16(wa[m], bh, acc[m], 0, 0, 0);
    }

    // epilogue: +bias +residual (from LDS), LN over h', write back to rs (cols wave-partitioned)
    float vals[6][4];
    float s = 0.f, q = 0.f;
    #pragma unroll
    for (int m = 0; m < 6; ++m) {
        float4 B4 = *(const float4*)(bout + m * 16 + g * 4);
        float bo[4] = {B4.x, B4.y, B4.z, B4.w};
        #pragma unroll
        for (int r = 0; r < 4; ++r) {
            int hr = m * 16 + g * 4 + r;
            float res = b2f(rs[hr * ZSTR2 + col]);
            float v = acc[m][r] + bo[r] + res;
            vals[m][r] = v;
            s += v; q += v * v;
        }
    }
    s += __shfl_xor(s, 16, 64); q += __shfl_xor(q, 16, 64);
    s += __shfl_xor(s, 32, 64); q += __shfl_xor(q, 32, 64);
    float mean = s * (1.0f / 96.0f);
    float var  = q * (1.0f / 96.0f) - mean * mean;
    float rstd = rsqrtf(var + 1e-5f);
    #pragma unroll
    for (int m = 0; m < 6; ++m) {
        float4 W4 = *(const float4*)(lnw + m * 16 + g * 4);
        float4 Bb = *(const float4*)(lnb + m * 16 + g * 4);
        float wv[4] = {W4.x, W4.y, W4.z, W4.w};
        float bv[4] = {Bb.x, Bb.y, Bb.z, Bb.w};
        #pragma unroll
        for (int r = 0; r < 4; ++r) {
            int hr = m * 16 + g * 4 + r;
            rs[hr * ZSTR2 + col] = bf16_rne(fmaf((vals[m][r] - mean) * rstd, wv[r], bv[r]));
        }
    }
    __syncthreads();
    for (int e = tid; e < 96 * 16; e += 512) {
        int hh = e >> 4, b8 = e & 15;
        u16x4 a = *(const u16x4*)(&rs[hh * ZSTR2 + b8 * 8]);
        u16x4 b = *(const u16x4*)(&rs[hh * ZSTR2 + b8 * 8 + 4]);
        u16x8 v = {a[0], a[1], a[2], a[3], b[0], b[1], b[2], b[3]};
        *(u16x8*)(hb2 + ((size_t)hh * L + l) * B + b0 + b8 * 8) = v;
    }
}

// ---------------- fc1 via MFMA (hi-only Wcomp), split-K over 42 ----------------
// grid: x = b-chunk (16), y = ksp (42) -> consecutive blocks share wcfrag reads (L2 reuse)
__launch_bounds__(256)
__global__ void fc1m_kernel(const unsigned short* __restrict__ hb2, const short* __restrict__ wcfrag,
                            float* __restrict__ partial)
{
    __shared__ __align__(16) unsigned short zs[H * ZSTR2];
    const int tid  = threadIdx.x;
    const int w    = tid >> 6;
    const int lane = tid & 63;
    const int g    = lane >> 4;
    const int cc   = lane & 15;
    const int ksp  = blockIdx.y;
    const int b0   = blockIdx.x * 128;

    f32x4 acc[2][6];
    #pragma unroll
    for (int n2 = 0; n2 < 2; ++n2)
        #pragma unroll
        for (int m = 0; m < 6; ++m) acc[n2][m] = (f32x4){0.f, 0.f, 0.f, 0.f};

    for (int il = 0; il < 4; ++il) {
        const int l = ksp * 4 + il;
        __syncthreads();
        for (int e = tid; e < 96 * 16; e += 256) {
            int hh = e >> 4, b8 = e & 15;
            u16x8 v = *(const u16x8*)(hb2 + ((size_t)hh * L + l) * B + b0 + b8 * 8);
            *(u16x4*)(&zs[hh * ZSTR2 + b8 * 8])     = (u16x4){v[0], v[1], v[2], v[3]};
            *(u16x4*)(&zs[hh * ZSTR2 + b8 * 8 + 4]) = (u16x4){v[4], v[5], v[6], v[7]};
        }
        __syncthreads();
        for (int ksl = 0; ksl < 3; ++ksl) {
            short8 bh[2];
            #pragma unroll
            for (int n2 = 0; n2 < 2; ++n2) {
                int col = (w * 2 + n2) * 16 + cc;
                #pragma unroll
                for (int j = 0; j < 8; ++j)
                    bh[n2][j] = (short)zs[(ksl * 32 + g * 8 + j) * ZSTR2 + col];
            }
            const short8* Wf = (const short8*)(wcfrag) + (size_t)(l * 3 + ksl) * 768;
            short8 wa[6];
            #pragma unroll
            for (int m = 0; m < 6; ++m) wa[m] = Wf[(2 * m) * 64 + lane];
            #pragma unroll
            for (int m = 0; m < 6; ++m) {
                #pragma unroll
                for (int n2 = 0; n2 < 2; ++n2)
                    acc[n2][m] = __builtin_amdgcn_mfma_f32_16x16x32_bf16(wa[m], bh[n2], acc[n2][m], 0, 0, 0);
            }
        }
    }

    #pragma unroll
    for (int n2 = 0; n2 < 2; ++n2) {
        int gb = b0 + (w * 2 + n2) * 16 + cc;
        #pragma unroll
        for (int m = 0; m < 6; ++m) {
            *(float4*)&partial[((size_t)ksp * B + gb) * 96 + m * 16 + g * 4] =
                make_float4(acc[n2][m][0], acc[n2][m][1], acc[n2][m][2], acc[n2][m][3]);
        }
    }
}

__global__ void fc1red_kernel(const float* __restrict__ partial, const float* __restrict__ cbias,
                              float* __restrict__ t1)
{
    int o = blockIdx.x * 256 + threadIdx.x;
    int p = o % 96;
    float s = cbias[p];
    #pragma unroll 6
    for (int k = 0; k < 42; ++k) s += partial[(size_t)k * (B * 96) + o];
    t1[o] = s;
}

__launch_bounds__(256)
__global__ void fc2_kernel(const float* __restrict__ t1, const float* __restrict__ W,
                           const float* __restrict__ fb, float* __restrict__ out)
{
    __shared__ float Ws[96 * 100];
    const int tid = threadIdx.x;
    for (int e = tid; e < 96 * 96; e += 256) Ws[(e / 96) * 100 + (e % 96)] = W[e];
    __syncthreads();
    int o = blockIdx.x * 256 + tid;
    int b = o / 96, p = o - b * 96;
    const float* tr = t1 + b * 96;
    float acc = fb[p];
    #pragma unroll 4
    for (int h = 0; h < 96; ++h) acc = fmaf(tr[h], Ws[h * 100 + p], acc);
    out[o] = acc;
}

extern "C" void kernel_launch(void* const* d_in, const int* in_sizes, int n_in,
                              void* d_out, int out_size, void* d_ws, size_t ws_size,
                              hipStream_t stream)
{
    const float* x      = (const float*)d_in[0];
    const float* encW   = (const float*)d_in[1];
    const float* encb   = (const float*)d_in[2];
    const float* log_dt = (const float*)d_in[3];
    const float* lar    = (const float*)d_in[4];
    const float* aim    = (const float*)d_in[5];
    const float* cre    = (const float*)d_in[6];
    const float* cim    = (const float*)d_in[7];
    const float* dsk    = (const float*)d_in[8];
    const float* wout   = (const float*)d_in[9];
    const float* boutp  = (const float*)d_in[10];
    const float* lnw    = (const float*)d_in[11];
    const float* lnb    = (const float*)d_in[12];
    const float* decW   = (const float*)d_in[13];
    const float* decb   = (const float*)d_in[14];
    const float* fc1W   = (const float*)d_in[15];
    const float* fc1b   = (const float*)d_in[16];
    const float* fc2W   = (const float*)d_in[17];
    const float* fc2b   = (const float*)d_in[18];

    // ws layout (max end = 143 MiB, proven envelope):
    char*           ws      = (char*)d_ws;
    float*          K       = (float*)(ws);                              // 258 KB
    short*          wfrag   = (short*)(ws + ((size_t)384 << 10));        // 147 KB
    float*          t1      = (float*)(ws + ((size_t)1 << 20));          // 786 KB
    float*          cbpart  = (float*)(ws + ((size_t)1 << 20) + (900 << 10)); // 64.5 KB
    float*          cbias   = (float*)(ws + ((size_t)1 << 20) + (980 << 10)); // 384 B
    short*          wcfrag  = (short*)(ws + ((size_t)2 << 20));          // 6.19 MB
    short*          tfrag   = (short*)(ws + ((size_t)9 << 20));          // 3.38 MB (hi-only)
    float*          wcs     = (float*)(ws + ((size_t)9 << 20));          // 6.19 MB, dead before tgen (alias)
    unsigned short* hb2     = (unsigned short*)(ws + ((size_t)16 << 20)); // 63.0 MiB (h,l,b) bf16
    unsigned short* z2      = (unsigned short*)(ws + ((size_t)80 << 20)); // 63.0 MiB (h,l,b) bf16
    float*          partial = (float*)(ws + ((size_t)80 << 20));          // 33 MiB, aliases z2

    kgen_kernel<<<NB * H, 64, 0, stream>>>(log_dt, lar, aim, cre, cim, K);
    wprep_kernel<<<144, 256, 0, stream>>>(wout, wfrag, NB * 9216);
    wcomp_kernel<<<L, 256, 0, stream>>>(decW, decb, fc1W, wcs, cbpart);
    wprep_kernel<<<6048, 256, 0, stream>>>(wcs, wcfrag, L * 9216);
    cbias_red_kernel<<<1, 128, 0, stream>>>(cbpart, fc1b, cbias);
    enc2_kernel<<<dim3(L, 8), 256, 0, stream>>>(x, encW, encb, hb2);
    for (int i = 0; i < NB; ++i) {
        tgen_kernel<<<1584, 256, 0, stream>>>(K + i * H * L, tfrag);
        conv3_kernel<<<dim3(32, 96), 256, 0, stream>>>(hb2, tfrag, dsk + i * H, z2);
        mix2_kernel<<<dim3(16, L), 512, 0, stream>>>(z2, hb2, wfrag + i * 18432,
                                                     boutp + i * H, lnw + i * H, lnb + i * H);
    }
    fc1m_kernel<<<dim3(16, 42), 256, 0, stream>>>(hb2, wcfrag, partial);
    fc1red_kernel<<<768, 256, 0, stream>>>(partial, cbias, t1);
    fc2_kernel<<<768, 256, 0, stream>>>(t1, fc2W, fc2b, (float*)d_out);
}

// Round 18
// 484.502 us; speedup vs baseline: 1.2760x; 1.0097x over previous
//
#include <hip/hip_runtime.h>
#include <hip/hip_bf16.h>
#include <math.h>

#define NB 4
#define B  2048
#define L  168
#define DI 9
#define H  96
#define N2 48

#define ZSTR2 132   // mix2/fc1m zs row stride (ushorts): 128 + 4 pad
#define CZ 68       // conv3 zs row stride (ushorts): 64 + 4 pad (conflict-free, verified r12)

typedef short short8 __attribute__((ext_vector_type(8)));
typedef float f32x4  __attribute__((ext_vector_type(4)));
typedef unsigned short u16x8 __attribute__((ext_vector_type(8)));
typedef unsigned short u16x4 __attribute__((ext_vector_type(4)));

// exact-algebra gelu: 0.5x(1+tanh(y)) == x*(1 - 1/(exp(2y)+1)), exp via native v_exp_f32 (2^x)
__device__ __forceinline__ float gelu_f(float x) {
    float x2 = x * x;
    float e  = __builtin_amdgcn_exp2f(x * fmaf(0.1029432225f, x2, 2.3022081899f));
    float r  = __builtin_amdgcn_rcpf(e + 1.0f);
    return x * (1.0f - r);
}

__device__ __forceinline__ unsigned short bf16_rne(float x) {
    unsigned u = __float_as_uint(x);
    return (unsigned short)((u + 0x7FFFu + ((u >> 16) & 1u)) >> 16);
}
__device__ __forceinline__ float b2f(unsigned short v) {
    return __uint_as_float((unsigned)v << 16);
}

// ---------------- S4D kernel generation: K[i][h][l] ----------------
__global__ void kgen_kernel(const float* __restrict__ log_dt, const float* __restrict__ lar,
                            const float* __restrict__ aim, const float* __restrict__ cre,
                            const float* __restrict__ cim, float* __restrict__ K)
{
    const int ih   = blockIdx.x;
    const int lane = threadIdx.x;
    float ctre = 0.f, ctim = 0.f, pre = 0.f, pim = 0.f, mre = 0.f, mim = 0.f;
    if (lane < N2) {
        float dt  = expf(log_dt[ih]);
        int   idx = ih * N2 + lane;
        float reA = -expf(lar[idx]);
        float imA = aim[idx];
        float dre = dt * reA, dim = dt * imA;
        float er  = expf(dre);
        float sv, cv;
        sincosf(dim, &sv, &cv);
        mre = er * cv; mim = er * sv;
        float nre = mre - 1.0f, nim = mim;
        float den = reA * reA + imA * imA;
        float tre = (nre * reA + nim * imA) / den;
        float tim = (nim * reA - nre * imA) / den;
        float cr = cre[idx], ci = cim[idx];
        ctre = cr * tre - ci * tim;
        ctim = cr * tim + ci * tre;
        pre = 1.0f; pim = 0.0f;
    }
    float* Kr = K + ih * L;
    for (int l = 0; l < L; ++l) {
        float term = ctre * pre - ctim * pim;
        #pragma unroll
        for (int off = 32; off > 0; off >>= 1) term += __shfl_xor(term, off, 64);
        if (lane == 0) Kr[l] = 2.0f * term;
        float nr = pre * mre - pim * mim;
        float ni = pre * mim + pim * mre;
        pre = nr; pim = ni;
    }
}

// ---------------- prepack W into MFMA A-frags, hi-block-contiguous: [layer][ch][s][m][lane] ----------------
__global__ void wprep_kernel(const float* __restrict__ wout, short* __restrict__ wfrag, int ntask)
{
    int idx = blockIdx.x * 256 + threadIdx.x;
    if (idx >= ntask) return;
    int layer = idx / 9216;  int rem  = idx - layer * 9216;
    int ch    = rem / 3072;  int rem2 = rem - ch * 3072;
    int m     = rem2 / 512;  int rem3 = rem2 - m * 512;
    int s     = rem3 / 256;  int rem4 = rem3 - s * 256;
    int lane  = rem4 / 4;    int d    = rem4 - lane * 4;
    int g = lane >> 4, c = lane & 15;
    int k  = ch * 32 + g * 8 + 2 * d;
    int hp = m * 16 + c;
    const float* Wl = wout + (size_t)layer * H * H;
    float w0 = Wl[k * H + hp];
    float w1 = Wl[(k + 1) * H + hp];
    unsigned short b0, b1;
    if (s == 0) { b0 = bf16_rne(w0); b1 = bf16_rne(w1); }
    else {
        unsigned short h0 = bf16_rne(w0), h1 = bf16_rne(w1);
        b0 = bf16_rne(w0 - b2f(h0));
        b1 = bf16_rne(w1 - b2f(h1));
    }
    // dst layout: [layer][ch][s][m][lane][4 dwords] -> hi frags contiguous per (layer,ch)
    size_t dst = ((((size_t)(layer * 3 + ch) * 2 + s) * 6 + m) * 64 + lane) * 8 + 2 * d;
    wfrag[dst]     = (short)b0;
    wfrag[dst + 1] = (short)b1;
}

// ---------------- Toeplitz A-fragments (hi-only bf16): T[l][l'] = K[l-l'] ----------------
__global__ void tgen_kernel(const float* __restrict__ Kg, short* __restrict__ tfrag)
{
    static const int kmaxA[11] = {0, 0, 1, 1, 2, 2, 3, 3, 4, 4, 5};
    static const int toffA[11] = {0, 1, 2, 4, 6, 9, 12, 16, 20, 25, 30};
    int idx = blockIdx.x * 256 + threadIdx.x;          // 96*66*64 tasks
    if (idx >= 96 * 66 * 64) return;
    int lane = idx & 63;
    int t    = (idx >> 6) % 66;
    int h    = (idx >> 6) / 66;
    int mi = t / 6, ki = t - mi * 6;
    if (ki > kmaxA[mi]) return;
    int g = lane >> 4, c = lane & 15;
    int row = mi * 16 + c;
    short8 a;
    #pragma unroll
    for (int j = 0; j < 8; ++j) {
        int kk = ki * 32 + g * 8 + j;
        int d  = row - kk;
        float val = (row < L && d >= 0) ? Kg[h * L + d] : 0.0f;
        a[j] = (short)bf16_rne(val);
    }
    short8* dst = (short8*)tfrag + (size_t)(h * 36 + toffA[mi] + ki) * 64;
    dst[lane] = a;
}

// ---------------- compose decW into fc1W ----------------
__launch_bounds__(256)
__global__ void wcomp_kernel(const float* __restrict__ decW, const float* __restrict__ decb,
                             const float* __restrict__ fc1W, float* __restrict__ wcs,
                             float* __restrict__ cbpart)
{
    __shared__ float Bs[96 * 100];
    const int tid = threadIdx.x;
    const int l   = blockIdx.x;
    for (int e = tid; e < 96 * 96; e += 256) {
        int h = e / 96, p = e - h * 96;
        Bs[h * 100 + p] = fc1W[(size_t)(l * 96 + h) * 96 + p];
    }
    __syncthreads();
    const int pt = tid & 31;
    const int kt = tid >> 5;
    float acc[12][3];
    #pragma unroll
    for (int kk = 0; kk < 12; ++kk)
        #pragma unroll
        for (int j = 0; j < 3; ++j) acc[kk][j] = 0.f;
    for (int h = 0; h < 96; ++h) {
        float dw[12];
        #pragma unroll
        for (int kk = 0; kk < 12; ++kk) dw[kk] = decW[(kt + 8 * kk) * 96 + h];
        float bs[3];
        #pragma unroll
        for (int j = 0; j < 3; ++j) bs[j] = Bs[h * 100 + pt + 32 * j];
        #pragma unroll
        for (int kk = 0; kk < 12; ++kk)
            #pragma unroll
            for (int j = 0; j < 3; ++j) acc[kk][j] = fmaf(dw[kk], bs[j], acc[kk][j]);
    }
    float* wl = wcs + (size_t)l * 9216;
    #pragma unroll
    for (int kk = 0; kk < 12; ++kk)
        #pragma unroll
        for (int j = 0; j < 3; ++j)
            wl[(kt + 8 * kk) * 96 + pt + 32 * j] = acc[kk][j];
    if (kt == 0) {
        #pragma unroll
        for (int j = 0; j < 3; ++j) {
            float s = 0.f;
            for (int h = 0; h < 96; ++h) s = fmaf(decb[h], Bs[h * 100 + pt + 32 * j], s);
            cbpart[l * 96 + pt + 32 * j] = s;
        }
    }
}

__global__ void cbias_red_kernel(const float* __restrict__ cbpart, const float* __restrict__ fc1b,
                                 float* __restrict__ cbias)
{
    int p = threadIdx.x;
    if (p < 96) {
        float s = fc1b[p];
        for (int l = 0; l < L; ++l) s += cbpart[l * 96 + p];
        cbias[p] = s;
    }
}

// ---------------- encoder into (h,l,b) bf16 ----------------
__launch_bounds__(256)
__global__ void enc2_kernel(const float* __restrict__ x, const float* __restrict__ W,
                            const float* __restrict__ bias, unsigned short* __restrict__ hb2)
{
    __shared__ float Ws[DI * H];
    __shared__ float bs[H];
    const int tid = threadIdx.x;
    const int l   = blockIdx.x;
    const int b0  = blockIdx.y * 256;
    for (int e = tid; e < DI * H; e += 256) Ws[e] = W[e];
    if (tid < H) bs[tid] = bias[tid];
    __syncthreads();
    float xv[DI];
    const float* xr = x + (size_t)(b0 + tid) * (L * DI) + l * DI;
    #pragma unroll
    for (int k = 0; k < DI; ++k) xv[k] = xr[k];
    for (int h = 0; h < H; ++h) {
        float a = bs[h];
        #pragma unroll
        for (int k = 0; k < DI; ++k) a = fmaf(xv[k], Ws[k * H + h], a);
        hb2[((size_t)h * L + l) * B + b0 + tid] = bf16_rne(a);
    }
}

// ---------------- conv via Toeplitz MFMA + skip + GELU: chunk 64, batched Tf loads, 6 blocks/CU ----------------
__launch_bounds__(256, 6)
__global__ void conv3_kernel(const unsigned short* __restrict__ hb2, const short* __restrict__ tfrag,
                             const float* __restrict__ Dsk, unsigned short* __restrict__ z2)
{
    static const int toffA[11] = {0, 1, 2, 4, 6, 9, 12, 16, 20, 25, 30};
    __shared__ __align__(16) unsigned short zs[192 * CZ];   // 26.1 KB
    const int tid  = threadIdx.x;
    const int w    = tid >> 6;
    const int lane = tid & 63;
    const int g    = lane >> 4;
    const int cc   = lane & 15;
    const int h    = blockIdx.y;
    const int b0   = blockIdx.x * 64;

    for (int e = tid; e < 168 * 8; e += 256) {
        int lp = e >> 3, b8 = e & 7;
        u16x8 v = *(const u16x8*)(hb2 + ((size_t)h * L + lp) * B + b0 + b8 * 8);
        *(u16x4*)(&zs[lp * CZ + b8 * 8])     = (u16x4){v[0], v[1], v[2], v[3]};
        *(u16x4*)(&zs[lp * CZ + b8 * 8 + 4]) = (u16x4){v[4], v[5], v[6], v[7]};
    }
    for (int e = tid; e < 24 * 8; e += 256) {
        int lp = 168 + (e >> 3), b8 = e & 7;
        *(u16x4*)(&zs[lp * CZ + b8 * 8])     = (u16x4){0, 0, 0, 0};
        *(u16x4*)(&zs[lp * CZ + b8 * 8 + 4]) = (u16x4){0, 0, 0, 0};
    }
    __syncthreads();

    f32x4 acc[11];
    #pragma unroll
    for (int mi = 0; mi < 11; ++mi) acc[mi] = (f32x4){0.f, 0.f, 0.f, 0.f};

    const int col = w * 16 + cc;
    const short8* Tbase = (const short8*)tfrag + (size_t)h * 36 * 64 + lane;

    #pragma unroll
    for (int ki = 0; ki < 6; ++ki) {
        short8 bh;
        #pragma unroll
        for (int j = 0; j < 8; ++j)
            bh[j] = (short)zs[(ki * 32 + g * 8 + j) * CZ + col];
        short8 tf[11];
        #pragma unroll
        for (int mi = 0; mi < 11; ++mi)
            if (mi >= 2 * ki)
                tf[mi] = Tbase[(size_t)(toffA[mi] + ki) * 64];
        #pragma unroll
        for (int mi = 0; mi < 11; ++mi)
            if (mi >= 2 * ki)
                acc[mi] = __builtin_amdgcn_mfma_f32_16x16x32_bf16(tf[mi], bh, acc[mi], 0, 0, 0);
    }

    const float ds = Dsk[h];
    #pragma unroll
    for (int mi = 0; mi < 11; ++mi) {
        #pragma unroll
        for (int r = 0; r < 4; ++r) {
            int l = mi * 16 + g * 4 + r;
            if (l < L) {
                float uu = b2f(zs[l * CZ + col]);
                float zv = gelu_f(fmaf(ds, uu, acc[mi][r]));
                zs[l * CZ + col] = bf16_rne(zv);
            }
        }
    }
    __syncthreads();
    for (int e = tid; e < 168 * 8; e += 256) {
        int lp = e >> 3, b8 = e & 7;
        u16x4 a = *(const u16x4*)(&zs[lp * CZ + b8 * 8]);
        u16x4 b = *(const u16x4*)(&zs[lp * CZ + b8 * 8 + 4]);
        u16x8 v = {a[0], a[1], a[2], a[3], b[0], b[1], b[2], b[3]};
        *(u16x8*)(z2 + ((size_t)h * L + lp) * B + b0 + b8 * 8) = v;
    }
}

// ---------------- W_out GEMM (hi-only W, contiguous frags) + bias + residual + LN ----------------
__launch_bounds__(512)
__global__ void mix2_kernel(const unsigned short* __restrict__ z2, unsigned short* __restrict__ hb2,
                            const short* __restrict__ wfrag, const float* __restrict__ bout,
                            const float* __restrict__ lnw, const float* __restrict__ lnb)
{
    __shared__ __align__(16) unsigned short zs[H * ZSTR2];   // z (MFMA B operand)
    __shared__ __align__(16) unsigned short rs[H * ZSTR2];   // residual in, LN output out
    const int tid  = threadIdx.x;
    const int w    = tid >> 6;
    const int lane = tid & 63;
    const int g    = lane >> 4;
    const int cc   = lane & 15;
    const int l    = blockIdx.y;
    const int b0   = blockIdx.x * 128;

    for (int e = tid; e < 96 * 16; e += 512) {
        int hh = e >> 4, b8 = e & 15;
        u16x8 v = *(const u16x8*)(z2 + ((size_t)hh * L + l) * B + b0 + b8 * 8);
        *(u16x4*)(&zs[hh * ZSTR2 + b8 * 8])     = (u16x4){v[0], v[1], v[2], v[3]};
        *(u16x4*)(&zs[hh * ZSTR2 + b8 * 8 + 4]) = (u16x4){v[4], v[5], v[6], v[7]};
    }
    for (int e = tid; e < 96 * 16; e += 512) {
        int hh = e >> 4, b8 = e & 15;
        u16x8 v = *(const u16x8*)(hb2 + ((size_t)hh * L + l) * B + b0 + b8 * 8);
        *(u16x4*)(&rs[hh * ZSTR2 + b8 * 8])     = (u16x4){v[0], v[1], v[2], v[3]};
        *(u16x4*)(&rs[hh * ZSTR2 + b8 * 8 + 4]) = (u16x4){v[4], v[5], v[6], v[7]};
    }
    __syncthreads();

    f32x4 acc[6];
    #pragma unroll
    for (int m = 0; m < 6; ++m) acc[m] = (f32x4){0.f, 0.f, 0.f, 0.f};

    const int col = w * 16 + cc;

    #pragma unroll
    for (int ks = 0; ks < 3; ++ks) {
        short8 bh;
        #pragma unroll
        for (int j = 0; j < 8; ++j)
            bh[j] = (short)zs[(ks * 32 + g * 8 + j) * ZSTR2 + col];
        const short8* Wf = (const short8*)(wfrag) + ks * 12 * 64;   // hi block first (contiguous)
        short8 wa[6];
        #pragma unroll
        for (int m = 0; m < 6; ++m) wa[m] = Wf[m * 64 + lane];
        #pragma unroll
        for (int m = 0; m < 6; ++m)
            acc[m] = __builtin_amdgcn_mfma_f32_16x16x32_bf16(wa[m], bh, acc[m], 0, 0, 0);
    }

    float vals[6][4];
    float s = 0.f, q = 0.f;
    #pragma unroll
    for (int m = 0; m < 6; ++m) {
        float4 B4 = *(const float4*)(bout + m * 16 + g * 4);
        float bo[4] = {B4.x, B4.y, B4.z, B4.w};
        #pragma unroll
        for (int r = 0; r < 4; ++r) {
            int hr = m * 16 + g * 4 + r;
            float res = b2f(rs[hr * ZSTR2 + col]);
            float v = acc[m][r] + bo[r] + res;
            vals[m][r] = v;
            s += v; q += v * v;
        }
    }
    s += __shfl_xor(s, 16, 64); q += __shfl_xor(q, 16, 64);
    s += __shfl_xor(s, 32, 64); q += __shfl_xor(q, 32, 64);
    float mean = s * (1.0f / 96.0f);
    float var  = q * (1.0f / 96.0f) - mean * mean;
    float rstd = rsqrtf(var + 1e-5f);
    #pragma unroll
    for (int m = 0; m < 6; ++m) {
        float4 W4 = *(const float4*)(lnw + m * 16 + g * 4);
        float4 Bb = *(const float4*)(lnb + m * 16 + g * 4);
        float wv[4] = {W4.x, W4.y, W4.z, W4.w};
        float bv[4] = {Bb.x, Bb.y, Bb.z, Bb.w};
        #pragma unroll
        for (int r = 0; r < 4; ++r) {
            int hr = m * 16 + g * 4 + r;
            rs[hr * ZSTR2 + col] = bf16_rne(fmaf((vals[m][r] - mean) * rstd, wv[r], bv[r]));
        }
    }
    __syncthreads();
    for (int e = tid; e < 96 * 16; e += 512) {
        int hh = e >> 4, b8 = e & 15;
        u16x4 a = *(const u16x4*)(&rs[hh * ZSTR2 + b8 * 8]);
        u16x4 b = *(const u16x4*)(&rs[hh * ZSTR2 + b8 * 8 + 4]);
        u16x8 v = {a[0], a[1], a[2], a[3], b[0], b[1], b[2], b[3]};
        *(u16x8*)(hb2 + ((size_t)hh * L + l) * B + b0 + b8 * 8) = v;
    }
}

// ---------------- fc1 via MFMA (hi-only Wcomp, contiguous frags), split-K over 42 ----------------
__launch_bounds__(256)
__global__ void fc1m_kernel(const unsigned short* __restrict__ hb2, const short* __restrict__ wcfrag,
                            float* __restrict__ partial)
{
    __shared__ __align__(16) unsigned short zs[H * ZSTR2];
    const int tid  = threadIdx.x;
    const int w    = tid >> 6;
    const int lane = tid & 63;
    const int g    = lane >> 4;
    const int cc   = lane & 15;
    const int ksp  = blockIdx.y;
    const int b0   = blockIdx.x * 128;

    f32x4 acc[2][6];
    #pragma unroll
    for (int n2 = 0; n2 < 2; ++n2)
        #pragma unroll
        for (int m = 0; m < 6; ++m) acc[n2][m] = (f32x4){0.f, 0.f, 0.f, 0.f};

    for (int il = 0; il < 4; ++il) {
        const int l = ksp * 4 + il;
        __syncthreads();
        for (int e = tid; e < 96 * 16; e += 256) {
            int hh = e >> 4, b8 = e & 15;
            u16x8 v = *(const u16x8*)(hb2 + ((size_t)hh * L + l) * B + b0 + b8 * 8);
            *(u16x4*)(&zs[hh * ZSTR2 + b8 * 8])     = (u16x4){v[0], v[1], v[2], v[3]};
            *(u16x4*)(&zs[hh * ZSTR2 + b8 * 8 + 4]) = (u16x4){v[4], v[5], v[6], v[7]};
        }
        __syncthreads();
        for (int ksl = 0; ksl < 3; ++ksl) {
            short8 bh[2];
            #pragma unroll
            for (int n2 = 0; n2 < 2; ++n2) {
                int col = (w * 2 + n2) * 16 + cc;
                #pragma unroll
                for (int j = 0; j < 8; ++j)
                    bh[n2][j] = (short)zs[(ksl * 32 + g * 8 + j) * ZSTR2 + col];
            }
            const short8* Wf = (const short8*)(wcfrag) + (size_t)(l * 3 + ksl) * 768;  // hi block first
            short8 wa[6];
            #pragma unroll
            for (int m = 0; m < 6; ++m) wa[m] = Wf[m * 64 + lane];
            #pragma unroll
            for (int m = 0; m < 6; ++m) {
                #pragma unroll
                for (int n2 = 0; n2 < 2; ++n2)
                    acc[n2][m] = __builtin_amdgcn_mfma_f32_16x16x32_bf16(wa[m], bh[n2], acc[n2][m], 0, 0, 0);
            }
        }
    }

    #pragma unroll
    for (int n2 = 0; n2 < 2; ++n2) {
        int gb = b0 + (w * 2 + n2) * 16 + cc;
        #pragma unroll
        for (int m = 0; m < 6; ++m) {
            *(float4*)&partial[((size_t)ksp * B + gb) * 96 + m * 16 + g * 4] =
                make_float4(acc[n2][m][0], acc[n2][m][1], acc[n2][m][2], acc[n2][m][3]);
        }
    }
}

__global__ void fc1red_kernel(const float* __restrict__ partial, const float* __restrict__ cbias,
                              float* __restrict__ t1)
{
    int o = blockIdx.x * 256 + threadIdx.x;
    int p = o % 96;
    float s = cbias[p];
    #pragma unroll 7
    for (int k = 0; k < 42; ++k) s += partial[(size_t)k * (B * 96) + o];
    t1[o] = s;
}

__launch_bounds__(256)
__global__ void fc2_kernel(const float* __restrict__ t1, const float* __restrict__ W,
                           const float* __restrict__ fb, float* __restrict__ out)
{
    __shared__ float Ws[96 * 100];
    const int tid = threadIdx.x;
    for (int e = tid; e < 96 * 96; e += 256) Ws[(e / 96) * 100 + (e % 96)] = W[e];
    __syncthreads();
    int o = blockIdx.x * 256 + tid;
    int b = o / 96, p = o - b * 96;
    const float* tr = t1 + b * 96;
    float acc = fb[p];
    #pragma unroll 4
    for (int h = 0; h < 96; ++h) acc = fmaf(tr[h], Ws[h * 100 + p], acc);
    out[o] = acc;
}

extern "C" void kernel_launch(void* const* d_in, const int* in_sizes, int n_in,
                              void* d_out, int out_size, void* d_ws, size_t ws_size,
                              hipStream_t stream)
{
    const float* x      = (const float*)d_in[0];
    const float* encW   = (const float*)d_in[1];
    const float* encb   = (const float*)d_in[2];
    const float* log_dt = (const float*)d_in[3];
    const float* lar    = (const float*)d_in[4];
    const float* aim    = (const float*)d_in[5];
    const float* cre    = (const float*)d_in[6];
    const float* cim    = (const float*)d_in[7];
    const float* dsk    = (const float*)d_in[8];
    const float* wout   = (const float*)d_in[9];
    const float* boutp  = (const float*)d_in[10];
    const float* lnw    = (const float*)d_in[11];
    const float* lnb    = (const float*)d_in[12];
    const float* decW   = (const float*)d_in[13];
    const float* decb   = (const float*)d_in[14];
    const float* fc1W   = (const float*)d_in[15];
    const float* fc1b   = (const float*)d_in[16];
    const float* fc2W   = (const float*)d_in[17];
    const float* fc2b   = (const float*)d_in[18];

    // ws layout (max end = 143 MiB, proven envelope):
    char*           ws      = (char*)d_ws;
    float*          K       = (float*)(ws);                              // 258 KB
    short*          wfrag   = (short*)(ws + ((size_t)384 << 10));        // 147 KB
    float*          t1      = (float*)(ws + ((size_t)1 << 20));          // 786 KB
    float*          cbpart  = (float*)(ws + ((size_t)1 << 20) + (900 << 10)); // 64.5 KB
    float*          cbias   = (float*)(ws + ((size_t)1 << 20) + (980 << 10)); // 384 B
    short*          wcfrag  = (short*)(ws + ((size_t)2 << 20));          // 6.19 MB
    short*          tfrag   = (short*)(ws + ((size_t)9 << 20));          // 3.38 MB (hi-only)
    float*          wcs     = (float*)(ws + ((size_t)9 << 20));          // 6.19 MB, dead before tgen (alias)
    unsigned short* hb2     = (unsigned short*)(ws + ((size_t)16 << 20)); // 63.0 MiB (h,l,b) bf16
    unsigned short* z2      = (unsigned short*)(ws + ((size_t)80 << 20)); // 63.0 MiB (h,l,b) bf16
    float*          partial = (float*)(ws + ((size_t)80 << 20));          // 33 MiB, aliases z2

    kgen_kernel<<<NB * H, 64, 0, stream>>>(log_dt, lar, aim, cre, cim, K);
    wprep_kernel<<<144, 256, 0, stream>>>(wout, wfrag, NB * 9216);
    wcomp_kernel<<<L, 256, 0, stream>>>(decW, decb, fc1W, wcs, cbpart);
    wprep_kernel<<<6048, 256, 0, stream>>>(wcs, wcfrag, L * 9216);
    cbias_red_kernel<<<1, 128, 0, stream>>>(cbpart, fc1b, cbias);
    enc2_kernel<<<dim3(L, 8), 256, 0, stream>>>(x, encW, encb, hb2);
    for (int i = 0; i < NB; ++i) {
        tgen_kernel<<<1584, 256, 0, stream>>>(K + i * H * L, tfrag);
        conv3_kernel<<<dim3(32, 96), 256, 0, stream>>>(hb2, tfrag, dsk + i * H, z2);
        mix2_kernel<<<dim3(16, L), 512, 0, stream>>>(z2, hb2, wfrag + i * 18432,
                                                     boutp + i * H, lnw + i * H, lnb + i * H);
    }
    fc1m_kernel<<<dim3(16, 42), 256, 0, stream>>>(hb2, wcfrag, partial);
    fc1red_kernel<<<768, 256, 0, stream>>>(partial, cbias, t1);
    fc2_kernel<<<768, 256, 0, stream>>>(t1, fc2W, fc2b, (float*)d_out);
}

// Round 19
// 479.047 us; speedup vs baseline: 1.2905x; 1.0114x over previous
//
#include <hip/hip_runtime.h>
#include <hip/hip_bf16.h>
#include <math.h>

#define NB 4
#define B  2048
#define L  168
#define DI 9
#define H  96
#define N2 48

#define ZSTR2 132   // mix2/fc1m zs row stride (ushorts): 128 + 4 pad
#define CZ 68       // conv3 zs row stride (ushorts): 64 + 4 pad (conflict-free, verified r12)

typedef short short8 __attribute__((ext_vector_type(8)));
typedef float f32x4  __attribute__((ext_vector_type(4)));
typedef unsigned short u16x8 __attribute__((ext_vector_type(8)));
typedef unsigned short u16x4 __attribute__((ext_vector_type(4)));

// exact-algebra gelu: 0.5x(1+tanh(y)) == x*(1 - 1/(exp(2y)+1)), exp via native v_exp_f32 (2^x)
__device__ __forceinline__ float gelu_f(float x) {
    float x2 = x * x;
    float e  = __builtin_amdgcn_exp2f(x * fmaf(0.1029432225f, x2, 2.3022081899f));
    float r  = __builtin_amdgcn_rcpf(e + 1.0f);
    return x * (1.0f - r);
}

__device__ __forceinline__ unsigned short bf16_rne(float x) {
    unsigned u = __float_as_uint(x);
    return (unsigned short)((u + 0x7FFFu + ((u >> 16) & 1u)) >> 16);
}
__device__ __forceinline__ float b2f(unsigned short v) {
    return __uint_as_float((unsigned)v << 16);
}

// ---------------- S4D kernel generation: K[i][h][l] ----------------
__global__ void kgen_kernel(const float* __restrict__ log_dt, const float* __restrict__ lar,
                            const float* __restrict__ aim, const float* __restrict__ cre,
                            const float* __restrict__ cim, float* __restrict__ K)
{
    const int ih   = blockIdx.x;
    const int lane = threadIdx.x;
    float ctre = 0.f, ctim = 0.f, pre = 0.f, pim = 0.f, mre = 0.f, mim = 0.f;
    if (lane < N2) {
        float dt  = expf(log_dt[ih]);
        int   idx = ih * N2 + lane;
        float reA = -expf(lar[idx]);
        float imA = aim[idx];
        float dre = dt * reA, dim = dt * imA;
        float er  = expf(dre);
        float sv, cv;
        sincosf(dim, &sv, &cv);
        mre = er * cv; mim = er * sv;
        float nre = mre - 1.0f, nim = mim;
        float den = reA * reA + imA * imA;
        float tre = (nre * reA + nim * imA) / den;
        float tim = (nim * reA - nre * imA) / den;
        float cr = cre[idx], ci = cim[idx];
        ctre = cr * tre - ci * tim;
        ctim = cr * tim + ci * tre;
        pre = 1.0f; pim = 0.0f;
    }
    float* Kr = K + ih * L;
    for (int l = 0; l < L; ++l) {
        float term = ctre * pre - ctim * pim;
        #pragma unroll
        for (int off = 32; off > 0; off >>= 1) term += __shfl_xor(term, off, 64);
        if (lane == 0) Kr[l] = 2.0f * term;
        float nr = pre * mre - pim * mim;
        float ni = pre * mim + pim * mre;
        pre = nr; pim = ni;
    }
}

// ---------------- prepack W into MFMA A-frags, hi-block-contiguous: [layer][ch][s][m][lane] ----------------
__global__ void wprep_kernel(const float* __restrict__ wout, short* __restrict__ wfrag, int ntask)
{
    int idx = blockIdx.x * 256 + threadIdx.x;
    if (idx >= ntask) return;
    int layer = idx / 9216;  int rem  = idx - layer * 9216;
    int ch    = rem / 3072;  int rem2 = rem - ch * 3072;
    int m     = rem2 / 512;  int rem3 = rem2 - m * 512;
    int s     = rem3 / 256;  int rem4 = rem3 - s * 256;
    int lane  = rem4 / 4;    int d    = rem4 - lane * 4;
    int g = lane >> 4, c = lane & 15;
    int k  = ch * 32 + g * 8 + 2 * d;
    int hp = m * 16 + c;
    const float* Wl = wout + (size_t)layer * H * H;
    float w0 = Wl[k * H + hp];
    float w1 = Wl[(k + 1) * H + hp];
    unsigned short b0, b1;
    if (s == 0) { b0 = bf16_rne(w0); b1 = bf16_rne(w1); }
    else {
        unsigned short h0 = bf16_rne(w0), h1 = bf16_rne(w1);
        b0 = bf16_rne(w0 - b2f(h0));
        b1 = bf16_rne(w1 - b2f(h1));
    }
    size_t dst = ((((size_t)(layer * 3 + ch) * 2 + s) * 6 + m) * 64 + lane) * 8 + 2 * d;
    wfrag[dst]     = (short)b0;
    wfrag[dst + 1] = (short)b1;
}

// ---------------- Toeplitz A-fragments (hi-only bf16): T[l][l'] = K[l-l'] ----------------
__global__ void tgen_kernel(const float* __restrict__ Kg, short* __restrict__ tfrag)
{
    static const int kmaxA[11] = {0, 0, 1, 1, 2, 2, 3, 3, 4, 4, 5};
    static const int toffA[11] = {0, 1, 2, 4, 6, 9, 12, 16, 20, 25, 30};
    int idx = blockIdx.x * 256 + threadIdx.x;          // 96*66*64 tasks
    if (idx >= 96 * 66 * 64) return;
    int lane = idx & 63;
    int t    = (idx >> 6) % 66;
    int h    = (idx >> 6) / 66;
    int mi = t / 6, ki = t - mi * 6;
    if (ki > kmaxA[mi]) return;
    int g = lane >> 4, c = lane & 15;
    int row = mi * 16 + c;
    short8 a;
    #pragma unroll
    for (int j = 0; j < 8; ++j) {
        int kk = ki * 32 + g * 8 + j;
        int d  = row - kk;
        float val = (row < L && d >= 0) ? Kg[h * L + d] : 0.0f;
        a[j] = (short)bf16_rne(val);
    }
    short8* dst = (short8*)tfrag + (size_t)(h * 36 + toffA[mi] + ki) * 64;
    dst[lane] = a;
}

// ---------------- compose decW into fc1W ----------------
__launch_bounds__(256)
__global__ void wcomp_kernel(const float* __restrict__ decW, const float* __restrict__ decb,
                             const float* __restrict__ fc1W, float* __restrict__ wcs,
                             float* __restrict__ cbpart)
{
    __shared__ float Bs[96 * 100];
    const int tid = threadIdx.x;
    const int l   = blockIdx.x;
    for (int e = tid; e < 96 * 96; e += 256) {
        int h = e / 96, p = e - h * 96;
        Bs[h * 100 + p] = fc1W[(size_t)(l * 96 + h) * 96 + p];
    }
    __syncthreads();
    const int pt = tid & 31;
    const int kt = tid >> 5;
    float acc[12][3];
    #pragma unroll
    for (int kk = 0; kk < 12; ++kk)
        #pragma unroll
        for (int j = 0; j < 3; ++j) acc[kk][j] = 0.f;
    for (int h = 0; h < 96; ++h) {
        float dw[12];
        #pragma unroll
        for (int kk = 0; kk < 12; ++kk) dw[kk] = decW[(kt + 8 * kk) * 96 + h];
        float bs[3];
        #pragma unroll
        for (int j = 0; j < 3; ++j) bs[j] = Bs[h * 100 + pt + 32 * j];
        #pragma unroll
        for (int kk = 0; kk < 12; ++kk)
            #pragma unroll
            for (int j = 0; j < 3; ++j) acc[kk][j] = fmaf(dw[kk], bs[j], acc[kk][j]);
    }
    float* wl = wcs + (size_t)l * 9216;
    #pragma unroll
    for (int kk = 0; kk < 12; ++kk)
        #pragma unroll
        for (int j = 0; j < 3; ++j)
            wl[(kt + 8 * kk) * 96 + pt + 32 * j] = acc[kk][j];
    if (kt == 0) {
        #pragma unroll
        for (int j = 0; j < 3; ++j) {
            float s = 0.f;
            for (int h = 0; h < 96; ++h) s = fmaf(decb[h], Bs[h * 100 + pt + 32 * j], s);
            cbpart[l * 96 + pt + 32 * j] = s;
        }
    }
}

__global__ void cbias_red_kernel(const float* __restrict__ cbpart, const float* __restrict__ fc1b,
                                 float* __restrict__ cbias)
{
    int p = threadIdx.x;
    if (p < 96) {
        float s = fc1b[p];
        for (int l = 0; l < L; ++l) s += cbpart[l * 96 + p];
        cbias[p] = s;
    }
}

// ---------------- encoder into (h,l,b) bf16 ----------------
__launch_bounds__(256)
__global__ void enc2_kernel(const float* __restrict__ x, const float* __restrict__ W,
                            const float* __restrict__ bias, unsigned short* __restrict__ hb2)
{
    __shared__ float Ws[DI * H];
    __shared__ float bs[H];
    const int tid = threadIdx.x;
    const int l   = blockIdx.x;
    const int b0  = blockIdx.y * 256;
    for (int e = tid; e < DI * H; e += 256) Ws[e] = W[e];
    if (tid < H) bs[tid] = bias[tid];
    __syncthreads();
    float xv[DI];
    const float* xr = x + (size_t)(b0 + tid) * (L * DI) + l * DI;
    #pragma unroll
    for (int k = 0; k < DI; ++k) xv[k] = xr[k];
    for (int h = 0; h < H; ++h) {
        float a = bs[h];
        #pragma unroll
        for (int k = 0; k < DI; ++k) a = fmaf(xv[k], Ws[k * H + h], a);
        hb2[((size_t)h * L + l) * B + b0 + tid] = bf16_rne(a);
    }
}

// ---------------- conv via Toeplitz MFMA + skip + GELU: XCD-swizzled, 6 blocks/CU ----------------
__launch_bounds__(256, 6)
__global__ void conv3_kernel(const unsigned short* __restrict__ hb2, const short* __restrict__ tfrag,
                             const float* __restrict__ Dsk, unsigned short* __restrict__ z2)
{
    static const int toffA[11] = {0, 1, 2, 4, 6, 9, 12, 16, 20, 25, 30};
    __shared__ __align__(16) unsigned short zs[192 * CZ];   // 26.1 KB
    const int tid  = threadIdx.x;
    const int w    = tid >> 6;
    const int lane = tid & 63;
    const int g    = lane >> 4;
    const int cc   = lane & 15;
    // XCD-aware bijective swizzle: nwg = 32*96 = 3072, 384 per XCD
    const int flat = blockIdx.y * 32 + blockIdx.x;
    const int work = (flat & 7) * 384 + (flat >> 3);
    const int h    = work >> 5;
    const int b0   = (work & 31) * 64;

    for (int e = tid; e < 168 * 8; e += 256) {
        int lp = e >> 3, b8 = e & 7;
        u16x8 v = *(const u16x8*)(hb2 + ((size_t)h * L + lp) * B + b0 + b8 * 8);
        *(u16x4*)(&zs[lp * CZ + b8 * 8])     = (u16x4){v[0], v[1], v[2], v[3]};
        *(u16x4*)(&zs[lp * CZ + b8 * 8 + 4]) = (u16x4){v[4], v[5], v[6], v[7]};
    }
    for (int e = tid; e < 24 * 8; e += 256) {
        int lp = 168 + (e >> 3), b8 = e & 7;
        *(u16x4*)(&zs[lp * CZ + b8 * 8])     = (u16x4){0, 0, 0, 0};
        *(u16x4*)(&zs[lp * CZ + b8 * 8 + 4]) = (u16x4){0, 0, 0, 0};
    }
    __syncthreads();

    f32x4 acc[11];
    #pragma unroll
    for (int mi = 0; mi < 11; ++mi) acc[mi] = (f32x4){0.f, 0.f, 0.f, 0.f};

    const int col = w * 16 + cc;
    const short8* Tbase = (const short8*)tfrag + (size_t)h * 36 * 64 + lane;

    #pragma unroll
    for (int ki = 0; ki < 6; ++ki) {
        short8 bh;
        #pragma unroll
        for (int j = 0; j < 8; ++j)
            bh[j] = (short)zs[(ki * 32 + g * 8 + j) * CZ + col];
        short8 tf[11];
        #pragma unroll
        for (int mi = 0; mi < 11; ++mi)
            if (mi >= 2 * ki)
                tf[mi] = Tbase[(size_t)(toffA[mi] + ki) * 64];
        #pragma unroll
        for (int mi = 0; mi < 11; ++mi)
            if (mi >= 2 * ki)
                acc[mi] = __builtin_amdgcn_mfma_f32_16x16x32_bf16(tf[mi], bh, acc[mi], 0, 0, 0);
    }

    const float ds = Dsk[h];
    #pragma unroll
    for (int mi = 0; mi < 11; ++mi) {
        #pragma unroll
        for (int r = 0; r < 4; ++r) {
            int l = mi * 16 + g * 4 + r;
            if (l < L) {
                float uu = b2f(zs[l * CZ + col]);
                float zv = gelu_f(fmaf(ds, uu, acc[mi][r]));
                zs[l * CZ + col] = bf16_rne(zv);
            }
        }
    }
    __syncthreads();
    for (int e = tid; e < 168 * 8; e += 256) {
        int lp = e >> 3, b8 = e & 7;
        u16x4 a = *(const u16x4*)(&zs[lp * CZ + b8 * 8]);
        u16x4 b = *(const u16x4*)(&zs[lp * CZ + b8 * 8 + 4]);
        u16x8 v = {a[0], a[1], a[2], a[3], b[0], b[1], b[2], b[3]};
        *(u16x8*)(z2 + ((size_t)h * L + lp) * B + b0 + b8 * 8) = v;
    }
}

// ---------------- W_out GEMM (hi-only W) + bias + residual + LN: XCD-swizzled ----------------
__launch_bounds__(512)
__global__ void mix2_kernel(const unsigned short* __restrict__ z2, unsigned short* __restrict__ hb2,
                            const short* __restrict__ wfrag, const float* __restrict__ bout,
                            const float* __restrict__ lnw, const float* __restrict__ lnb)
{
    __shared__ __align__(16) unsigned short zs[H * ZSTR2];   // z (MFMA B operand)
    __shared__ __align__(16) unsigned short rs[H * ZSTR2];   // residual in, LN output out
    const int tid  = threadIdx.x;
    const int w    = tid >> 6;
    const int lane = tid & 63;
    const int g    = lane >> 4;
    const int cc   = lane & 15;
    // XCD-aware bijective swizzle: nwg = 16*168 = 2688, 336 per XCD
    const int flat = blockIdx.y * 16 + blockIdx.x;
    const int work = (flat & 7) * 336 + (flat >> 3);
    const int l    = work >> 4;
    const int b0   = (work & 15) * 128;

    for (int e = tid; e < 96 * 16; e += 512) {
        int hh = e >> 4, b8 = e & 15;
        u16x8 v = *(const u16x8*)(z2 + ((size_t)hh * L + l) * B + b0 + b8 * 8);
        *(u16x4*)(&zs[hh * ZSTR2 + b8 * 8])     = (u16x4){v[0], v[1], v[2], v[3]};
        *(u16x4*)(&zs[hh * ZSTR2 + b8 * 8 + 4]) = (u16x4){v[4], v[5], v[6], v[7]};
    }
    for (int e = tid; e < 96 * 16; e += 512) {
        int hh = e >> 4, b8 = e & 15;
        u16x8 v = *(const u16x8*)(hb2 + ((size_t)hh * L + l) * B + b0 + b8 * 8);
        *(u16x4*)(&rs[hh * ZSTR2 + b8 * 8])     = (u16x4){v[0], v[1], v[2], v[3]};
        *(u16x4*)(&rs[hh * ZSTR2 + b8 * 8 + 4]) = (u16x4){v[4], v[5], v[6], v[7]};
    }
    __syncthreads();

    f32x4 acc[6];
    #pragma unroll
    for (int m = 0; m < 6; ++m) acc[m] = (f32x4){0.f, 0.f, 0.f, 0.f};

    const int col = w * 16 + cc;

    #pragma unroll
    for (int ks = 0; ks < 3; ++ks) {
        short8 bh;
        #pragma unroll
        for (int j = 0; j < 8; ++j)
            bh[j] = (short)zs[(ks * 32 + g * 8 + j) * ZSTR2 + col];
        const short8* Wf = (const short8*)(wfrag) + ks * 12 * 64;   // hi block first (contiguous)
        short8 wa[6];
        #pragma unroll
        for (int m = 0; m < 6; ++m) wa[m] = Wf[m * 64 + lane];
        #pragma unroll
        for (int m = 0; m < 6; ++m)
            acc[m] = __builtin_amdgcn_mfma_f32_16x16x32_bf16(wa[m], bh, acc[m], 0, 0, 0);
    }

    float vals[6][4];
    float s = 0.f, q = 0.f;
    #pragma unroll
    for (int m = 0; m < 6; ++m) {
        float4 B4 = *(const float4*)(bout + m * 16 + g * 4);
        float bo[4] = {B4.x, B4.y, B4.z, B4.w};
        #pragma unroll
        for (int r = 0; r < 4; ++r) {
            int hr = m * 16 + g * 4 + r;
            float res = b2f(rs[hr * ZSTR2 + col]);
            float v = acc[m][r] + bo[r] + res;
            vals[m][r] = v;
            s += v; q += v * v;
        }
    }
    s += __shfl_xor(s, 16, 64); q += __shfl_xor(q, 16, 64);
    s += __shfl_xor(s, 32, 64); q += __shfl_xor(q, 32, 64);
    float mean = s * (1.0f / 96.0f);
    float var  = q * (1.0f / 96.0f) - mean * mean;
    float rstd = rsqrtf(var + 1e-5f);
    #pragma unroll
    for (int m = 0; m < 6; ++m) {
        float4 W4 = *(const float4*)(lnw + m * 16 + g * 4);
        float4 Bb = *(const float4*)(lnb + m * 16 + g * 4);
        float wv[4] = {W4.x, W4.y, W4.z, W4.w};
        float bv[4] = {Bb.x, Bb.y, Bb.z, Bb.w};
        #pragma unroll
        for (int r = 0; r < 4; ++r) {
            int hr = m * 16 + g * 4 + r;
            rs[hr * ZSTR2 + col] = bf16_rne(fmaf((vals[m][r] - mean) * rstd, wv[r], bv[r]));
        }
    }
    __syncthreads();
    for (int e = tid; e < 96 * 16; e += 512) {
        int hh = e >> 4, b8 = e & 15;
        u16x4 a = *(const u16x4*)(&rs[hh * ZSTR2 + b8 * 8]);
        u16x4 b = *(const u16x4*)(&rs[hh * ZSTR2 + b8 * 8 + 4]);
        u16x8 v = {a[0], a[1], a[2], a[3], b[0], b[1], b[2], b[3]};
        *(u16x8*)(hb2 + ((size_t)hh * L + l) * B + b0 + b8 * 8) = v;
    }
}

// ---------------- fc1 via MFMA (hi-only Wcomp), split-K over 42, XCD-swizzled ----------------
__launch_bounds__(256)
__global__ void fc1m_kernel(const unsigned short* __restrict__ hb2, const short* __restrict__ wcfrag,
                            float* __restrict__ partial)
{
    __shared__ __align__(16) unsigned short zs[H * ZSTR2];
    const int tid  = threadIdx.x;
    const int w    = tid >> 6;
    const int lane = tid & 63;
    const int g    = lane >> 4;
    const int cc   = lane & 15;
    // XCD-aware bijective swizzle: nwg = 16*42 = 672, 84 per XCD
    const int flat = blockIdx.y * 16 + blockIdx.x;
    const int work = (flat & 7) * 84 + (flat >> 3);
    const int ksp  = work >> 4;
    const int b0   = (work & 15) * 128;

    f32x4 acc[2][6];
    #pragma unroll
    for (int n2 = 0; n2 < 2; ++n2)
        #pragma unroll
        for (int m = 0; m < 6; ++m) acc[n2][m] = (f32x4){0.f, 0.f, 0.f, 0.f};

    for (int il = 0; il < 4; ++il) {
        const int l = ksp * 4 + il;
        __syncthreads();
        for (int e = tid; e < 96 * 16; e += 256) {
            int hh = e >> 4, b8 = e & 15;
            u16x8 v = *(const u16x8*)(hb2 + ((size_t)hh * L + l) * B + b0 + b8 * 8);
            *(u16x4*)(&zs[hh * ZSTR2 + b8 * 8])     = (u16x4){v[0], v[1], v[2], v[3]};
            *(u16x4*)(&zs[hh * ZSTR2 + b8 * 8 + 4]) = (u16x4){v[4], v[5], v[6], v[7]};
        }
        __syncthreads();
        for (int ksl = 0; ksl < 3; ++ksl) {
            short8 bh[2];
            #pragma unroll
            for (int n2 = 0; n2 < 2; ++n2) {
                int col = (w * 2 + n2) * 16 + cc;
                #pragma unroll
                for (int j = 0; j < 8; ++j)
                    bh[n2][j] = (short)zs[(ksl * 32 + g * 8 + j) * ZSTR2 + col];
            }
            const short8* Wf = (const short8*)(wcfrag) + (size_t)(l * 3 + ksl) * 768;  // hi block first
            short8 wa[6];
            #pragma unroll
            for (int m = 0; m < 6; ++m) wa[m] = Wf[m * 64 + lane];
            #pragma unroll
            for (int m = 0; m < 6; ++m) {
                #pragma unroll
                for (int n2 = 0; n2 < 2; ++n2)
                    acc[n2][m] = __builtin_amdgcn_mfma_f32_16x16x32_bf16(wa[m], bh[n2], acc[n2][m], 0, 0, 0);
            }
        }
    }

    #pragma unroll
    for (int n2 = 0; n2 < 2; ++n2) {
        int gb = b0 + (w * 2 + n2) * 16 + cc;
        #pragma unroll
        for (int m = 0; m < 6; ++m) {
            *(float4*)&partial[((size_t)ksp * B + gb) * 96 + m * 16 + g * 4] =
                make_float4(acc[n2][m][0], acc[n2][m][1], acc[n2][m][2], acc[n2][m][3]);
        }
    }
}

__global__ void fc1red_kernel(const float* __restrict__ partial, const float* __restrict__ cbias,
                              float* __restrict__ t1)
{
    int o = blockIdx.x * 256 + threadIdx.x;
    int p = o % 96;
    float s = cbias[p];
    #pragma unroll 7
    for (int k = 0; k < 42; ++k) s += partial[(size_t)k * (B * 96) + o];
    t1[o] = s;
}

__launch_bounds__(256)
__global__ void fc2_kernel(const float* __restrict__ t1, const float* __restrict__ W,
                           const float* __restrict__ fb, float* __restrict__ out)
{
    __shared__ float Ws[96 * 100];
    const int tid = threadIdx.x;
    for (int e = tid; e < 96 * 96; e += 256) Ws[(e / 96) * 100 + (e % 96)] = W[e];
    __syncthreads();
    int o = blockIdx.x * 256 + tid;
    int b = o / 96, p = o - b * 96;
    const float* tr = t1 + b * 96;
    float acc = fb[p];
    #pragma unroll 4
    for (int h = 0; h < 96; ++h) acc = fmaf(tr[h], Ws[h * 100 + p], acc);
    out[o] = acc;
}

extern "C" void kernel_launch(void* const* d_in, const int* in_sizes, int n_in,
                              void* d_out, int out_size, void* d_ws, size_t ws_size,
                              hipStream_t stream)
{
    const float* x      = (const float*)d_in[0];
    const float* encW   = (const float*)d_in[1];
    const float* encb   = (const float*)d_in[2];
    const float* log_dt = (const float*)d_in[3];
    const float* lar    = (const float*)d_in[4];
    const float* aim    = (const float*)d_in[5];
    const float* cre    = (const float*)d_in[6];
    const float* cim    = (const float*)d_in[7];
    const float* dsk    = (const float*)d_in[8];
    const float* wout   = (const float*)d_in[9];
    const float* boutp  = (const float*)d_in[10];
    const float* lnw    = (const float*)d_in[11];
    const float* lnb    = (const float*)d_in[12];
    const float* decW   = (const float*)d_in[13];
    const float* decb   = (const float*)d_in[14];
    const float* fc1W   = (const float*)d_in[15];
    const float* fc1b   = (const float*)d_in[16];
    const float* fc2W   = (const float*)d_in[17];
    const float* fc2b   = (const float*)d_in[18];

    // ws layout (max end = 143 MiB, proven envelope):
    char*           ws      = (char*)d_ws;
    float*          K       = (float*)(ws);                              // 258 KB
    short*          wfrag   = (short*)(ws + ((size_t)384 << 10));        // 147 KB
    float*          t1      = (float*)(ws + ((size_t)1 << 20));          // 786 KB
    float*          cbpart  = (float*)(ws + ((size_t)1 << 20) + (900 << 10)); // 64.5 KB
    float*          cbias   = (float*)(ws + ((size_t)1 << 20) + (980 << 10)); // 384 B
    short*          wcfrag  = (short*)(ws + ((size_t)2 << 20));          // 6.19 MB
    short*          tfrag   = (short*)(ws + ((size_t)9 << 20));          // 3.38 MB (hi-only)
    float*          wcs     = (float*)(ws + ((size_t)9 << 20));          // 6.19 MB, dead before tgen (alias)
    unsigned short* hb2     = (unsigned short*)(ws + ((size_t)16 << 20)); // 63.0 MiB (h,l,b) bf16
    unsigned short* z2      = (unsigned short*)(ws + ((size_t)80 << 20)); // 63.0 MiB (h,l,b) bf16
    float*          partial = (float*)(ws + ((size_t)80 << 20));          // 33 MiB, aliases z2

    kgen_kernel<<<NB * H, 64, 0, stream>>>(log_dt, lar, aim, cre, cim, K);
    wprep_kernel<<<144, 256, 0, stream>>>(wout, wfrag, NB * 9216);
    wcomp_kernel<<<L, 256, 0, stream>>>(decW, decb, fc1W, wcs, cbpart);
    wprep_kernel<<<6048, 256, 0, stream>>>(wcs, wcfrag, L * 9216);
    cbias_red_kernel<<<1, 128, 0, stream>>>(cbpart, fc1b, cbias);
    enc2_kernel<<<dim3(L, 8), 256, 0, stream>>>(x, encW, encb, hb2);
    for (int i = 0; i < NB; ++i) {
        tgen_kernel<<<1584, 256, 0, stream>>>(K + i * H * L, tfrag);
        conv3_kernel<<<dim3(32, 96), 256, 0, stream>>>(hb2, tfrag, dsk + i * H, z2);
        mix2_kernel<<<dim3(16, L), 512, 0, stream>>>(z2, hb2, wfrag + i * 18432,
                                                     boutp + i * H, lnw + i * H, lnb + i * H);
    }
    fc1m_kernel<<<dim3(16, 42), 256, 0, stream>>>(hb2, wcfrag, partial);
    fc1red_kernel<<<768, 256, 0, stream>>>(partial, cbias, t1);
    fc2_kernel<<<768, 256, 0, stream>>>(t1, fc2W, fc2b, (float*)d_out);
}